// Round 16
// baseline (357.753 us; speedup 1.0000x reference)
//
#include <hip/hip_runtime.h>
#include <math.h>

constexpr int cN = 2, cH = 8, cL = 2048, cS = 2048, cE = 64, cD = 64;
constexpr int cC = 128, cK = 32, cB = 32, cIT = 10;
constexpr int cNH = cN * cH;          // 16
constexpr int SK = 8;                 // split-K factor for PV
constexpr int CHUNK = cS / SK;        // 256 s per split
constexpr int NT = 16;                // point tiles per nh (128 points each)
constexpr int HW = cC * 33;           // hist words: sbs[128][32] + scnt[128] = 4224
constexpr int PARTSZ = 32;            // members per k_out work item
constexpr int SLOTS = 256;            // schedule slots per nh (max 192 used)
constexpr int NBUF = cIT + 1;         // 11 ghist buffers (one per iteration)
// TEMP = 1/sqrt(64) = 0.125 exactly

// ---------------- Kernel 1: LSH bits + zero ghist ------------------------
__global__ __launch_bounds__(256)
void k_bits(const float* __restrict__ q, const float* __restrict__ planes,
            unsigned int* __restrict__ bits, int* __restrict__ ghist)
{
    __shared__ float pl[cB * 68];               // padded rows, 16B-aligned
    int tid = threadIdx.x;
    for (int i = tid; i < cB * (cE + 1); i += 256) {
        int b = i / 65, e = i % 65;
        pl[b * 68 + e] = planes[i];
    }
    {   // zero my slice of the 11 global hist buffers
        const int ZS = NBUF * cNH * HW / 128;   // 5808 (grid = 128 blocks)
        for (int i = tid; i < ZS; i += 256) ghist[(size_t)blockIdx.x * ZS + i] = 0;
    }
    __syncthreads();
    int idx = blockIdx.x * 256 + tid;           // (n*H + h)*L + l
    int l = idx % cL, h = (idx / cL) % cH, n = idx / (cL * cH);
    const float* qr = q + (((size_t)n * cL + l) * cH + h) * cE;
    float qv[cE];
#pragma unroll
    for (int e4 = 0; e4 < cE / 4; ++e4) {
        float4 f = ((const float4*)qr)[e4];
        qv[4*e4+0] = f.x; qv[4*e4+1] = f.y; qv[4*e4+2] = f.z; qv[4*e4+3] = f.w;
    }
    unsigned int w = 0;
    for (int b = 0; b < cB; ++b) {
        const float4* pr = (const float4*)(pl + b * 68);
        float acc = 0.f;
#pragma unroll
        for (int e4 = 0; e4 < cE / 4; ++e4) {
            float4 f = pr[e4];
            acc = fmaf(qv[4*e4+0], f.x, acc);
            acc = fmaf(qv[4*e4+1], f.y, acc);
            acc = fmaf(qv[4*e4+2], f.z, acc);
            acc = fmaf(qv[4*e4+3], f.w, acc);
        }
        acc += pl[b * 68 + 64];
        if (acc > 0.f) w |= (1u << b);
    }
    bits[idx] = w;
}

// ---------------- Kernel 2: one Lloyd iteration (update fused in) --------
// grid = 16 nh x 16 tiles = 256 blocks x 128 thr (1 point/thread).
// scb_it recomputed locally (cents[it-1] + ghist[it-1], integer-exact);
// tile 0 writes cents[it]. Last call (it==cIT) writes cl + pcounts.
__global__ __launch_bounds__(128)
void k_lloyd(const unsigned int* __restrict__ bits, int* __restrict__ ghist,
             unsigned int* __restrict__ cents, int* __restrict__ cl,
             int* __restrict__ pcounts, int it)
{
    __shared__ unsigned int scb[cC] __attribute__((aligned(16)));
    __shared__ int hist[HW];
    int tid = threadIdx.x, lane = tid & 63;
    int tile = blockIdx.x & (NT - 1), nh = blockIdx.x / NT;
    // ---- reconstruct scb_it (identical in every block of this nh) -------
    if (it == 0) {
        if (tid < cC) {
            // linspace(0,L-1,C).astype(int32): floor(c*2047/127), endpoint exact
            int i0 = (int)(((double)tid * 2047.0) / 127.0);
            scb[tid] = bits[(size_t)nh * cL + i0];
        }
    } else {
        const unsigned int* cp = cents + (size_t)(it - 1) * cNH * cC + nh * cC;
        const int* gb = ghist + (size_t)((it - 1) * cNH + nh) * HW;
        if (tid < cC) {
            unsigned int oldc = cp[tid];
            int cnt = gb[4096 + tid];
            if (cnt > 0) {
                unsigned int nw = 0;
#pragma unroll
                for (int b = 0; b < cB; ++b)
                    if (2 * gb[tid * 32 + b] > cnt) nw |= (1u << b);
                oldc = nw;
            }
            scb[tid] = oldc;
        }
    }
    for (int i = tid; i < HW; i += 128) hist[i] = 0;
    int l = tile * 128 + tid;
    unsigned int w = bits[(size_t)nh * cL + l];
    // per-lane bit ballots (lane b&31 keeps bit b of this wave's points)
    unsigned long long mymb = 0ull;
#pragma unroll
    for (int b = 0; b < cB; ++b) {
        unsigned long long m = __ballot((w >> b) & 1u);
        if ((lane & 31) == b) mymb = m;
    }
    __syncthreads();
    if (tile == 0 && it < cIT && tid < cC)
        cents[(size_t)it * cNH * cC + nh * cC + tid] = scb[tid];
    // ---- assignment: packed (hamming<<8)|c min; tie -> lowest c ---------
    const uint4* scb4 = (const uint4*)scb;
    int best = 0x7fffffff;
    for (int c4 = 0; c4 < cC / 4; ++c4) {
        uint4 cb = scb4[c4];
        int c = c4 * 4;
        best = min(best, (__popc(w ^ cb.x) << 8) | c);
        best = min(best, (__popc(w ^ cb.y) << 8) | (c + 1));
        best = min(best, (__popc(w ^ cb.z) << 8) | (c + 2));
        best = min(best, (__popc(w ^ cb.w) << 8) | (c + 3));
    }
    int bc = best & 255;
    if (it == cIT) cl[(size_t)nh * cL + l] = bc;
    // ---- wave-aggregated histogram into LDS -----------------------------
    for (int c = 0; c < cC; ++c) {
        unsigned long long m = __ballot(bc == c);
        if (m) {
            if (lane < cB) {
                int contrib = __popcll(m & mymb);
                if (contrib) atomicAdd(&hist[c * 32 + lane], contrib);
            }
            if (lane == 63) atomicAdd(&hist[4096 + c], __popcll(m));
        }
    }
    __syncthreads();
    // ---- flush nonzero to this iteration's global buffer ----------------
    int* gb = ghist + (size_t)(it * cNH + nh) * HW;
    for (int i = tid; i < HW; i += 128) {
        int v = hist[i];
        if (v) atomicAdd(&gb[i], v);
    }
    if (it == cIT && tid < cC)
        pcounts[(nh * NT + tile) * cC + tid] = hist[4096 + tid];
}

// ---------------- Kernel 2c: rank + (tile0) counts/moff/sched ------------
// grid = 16 nh x 16 tiles = 256 blocks x 128 thr (1 point/thread).
// Each block recomputes counts/moff locally from pcounts (integer-exact).
__global__ __launch_bounds__(128)
void k_rank(const int* __restrict__ cl, const int* __restrict__ pcounts,
            int* __restrict__ counts, int* __restrict__ moff,
            int* __restrict__ sched, int* __restrict__ mlist)
{
    __shared__ int pre[cC];       // exclusive prefix of full counts
    __shared__ int scn[cC];       // full counts
    __shared__ int sbefore[cC];   // sum of pcounts for tiles < mine
    __shared__ int wcnt0[cC];
    int tid = threadIdx.x, lane = tid & 63, wid = tid >> 6;
    int tile = blockIdx.x & (NT - 1), nh = blockIdx.x / NT;
    if (tid < cC) {
        int tot = 0, bef = 0;
        for (int t = 0; t < NT; ++t) {
            int v = pcounts[(nh * NT + t) * cC + tid];
            if (t < tile) bef += v;
            tot += v;
        }
        scn[tid] = tot;
        sbefore[tid] = bef;
    }
    __syncthreads();
    if (tid == 0) {
        int run = 0;
        for (int i = 0; i < cC; ++i) { pre[i] = run; run += scn[i]; }
    }
    __syncthreads();
    if (tile == 0) {                              // block-uniform branch
        if (tid < cC) {
            counts[nh * cC + tid] = scn[tid];
            moff[nh * cC + tid] = pre[tid];
        }
        sched[nh * SLOTS + tid] = -1;
        sched[nh * SLOTS + 128 + tid] = -1;
        __syncthreads();
        if (tid == 0) {
            int slot = 0;
            for (int i = 0; i < cC; ++i) {
                int np = (scn[i] + PARTSZ - 1) / PARTSZ;
                for (int p = 0; p < np; ++p)
                    sched[nh * SLOTS + slot++] = i | (p << 8);
            }
        }
    }
    int l = tile * 128 + tid;
    int bc = cl[(size_t)nh * cL + l];
    unsigned long long ltmask = (1ull << lane) - 1ull;
    int myrank = 0;
    for (int c = 0; c < cC; ++c) {
        unsigned long long m = __ballot(bc == c);
        if (wid == 0 && lane == 0) wcnt0[c] = __popcll(m);
        if (bc == c) myrank = __popcll(m & ltmask);
    }
    __syncthreads();
    int off = pre[bc] + sbefore[bc] + myrank + (wid == 1 ? wcnt0[bc] : 0);
    mlist[(size_t)nh * cL + off] = l;
}

// ---------------- Kernel 3: cluster-mean queries Qg ----------------------
// one block (64 lanes = e) per (nh,c); strict ascending-l chain (bit-exact)
__global__ __launch_bounds__(64)
void k_qg(const float* __restrict__ q, const int* __restrict__ mlist,
          const int* __restrict__ moff, const int* __restrict__ counts,
          float* __restrict__ Qg)
{
    int b = blockIdx.x;                 // nh*cC + c
    int nh = b >> 7;
    int h = nh % cH, n = nh / cH;
    int lane = threadIdx.x;
    int off = moff[b];
    int cnt = counts[b];
    const int* ml = mlist + (size_t)nh * cL + off;
    const float* qb = q + ((size_t)n * cL * cH + h) * cE + lane;
    float acc = 0.f;
    int j = 0;
    for (; j + 4 <= cnt; j += 4) {
        int i0 = ml[j], i1 = ml[j + 1], i2 = ml[j + 2], i3 = ml[j + 3];
        float v0 = qb[(size_t)i0 * cH * cE];
        float v1 = qb[(size_t)i1 * cH * cE];
        float v2 = qb[(size_t)i2 * cH * cE];
        float v3 = qb[(size_t)i3 * cH * cE];
        acc += v0; acc += v1; acc += v2; acc += v3;    // in-order chain
    }
    for (; j < cnt; ++j) acc += qb[(size_t)ml[j] * cH * cE];
    float cs = (float)(cnt > 0 ? cnt : 1);
    Qg[(size_t)b * cE + lane] = acc / cs;
}

// ---------------- Kernel 4a: QK = Qg . k^T  (tiled GEMM, exact chains) ---
__global__ __launch_bounds__(256)
void k_qk_gemm(const float* __restrict__ key, const float* __restrict__ Qg,
               float* __restrict__ QK)
{
    __shared__ float qgT[cE][cC + 2];      // [e][c]
    __shared__ float kT[cE][128 + 2];      // [e][s_local]
    int tid = threadIdx.x;
    int bs = blockIdx.x & 15;              // s-tile
    int nh = blockIdx.x >> 4;
    int h = nh % cH, n = nh / cH;
    const float4* qsrc = (const float4*)(Qg + (size_t)nh * cC * cE);
#pragma unroll
    for (int i = 0; i < 8; ++i) {
        int f = tid + 256 * i;
        int c = f >> 4, e4 = (f & 15) << 2;
        float4 v = qsrc[f];
        qgT[e4+0][c] = v.x; qgT[e4+1][c] = v.y; qgT[e4+2][c] = v.z; qgT[e4+3][c] = v.w;
    }
    const float* kb = key + (size_t)n * cS * cH * cE + (size_t)h * cE;
    int s0 = bs * 128;
#pragma unroll
    for (int i = 0; i < 8; ++i) {
        int f = tid + 256 * i;
        int s = f >> 4, e4 = (f & 15) << 2;
        float4 v = *(const float4*)(kb + (size_t)(s0 + s) * (cH * cE) + e4);
        kT[e4+0][s] = v.x; kT[e4+1][s] = v.y; kT[e4+2][s] = v.z; kT[e4+3][s] = v.w;
    }
    __syncthreads();
    int tx = tid & 15, ty = tid >> 4;
    float acc[8][8];
#pragma unroll
    for (int i = 0; i < 8; ++i)
#pragma unroll
        for (int j = 0; j < 8; ++j) acc[i][j] = 0.f;
    for (int e = 0; e < cE; ++e) {
        float qv[8], kv[8];
#pragma unroll
        for (int i = 0; i < 8; ++i) qv[i] = qgT[e][ty + 16 * i];
#pragma unroll
        for (int j = 0; j < 8; ++j) kv[j] = kT[e][tx + 16 * j];
#pragma unroll
        for (int i = 0; i < 8; ++i)
#pragma unroll
            for (int j = 0; j < 8; ++j)
                acc[i][j] = fmaf(qv[i], kv[j], acc[i][j]);   // ascending-e chain
    }
    float* dst = QK + (size_t)nh * cC * cS + s0;
#pragma unroll
    for (int i = 0; i < 8; ++i)
#pragma unroll
        for (int j = 0; j < 8; ++j)
            dst[(size_t)(ty + 16 * i) * cS + tx + 16 * j] = acc[i][j];
}

// ---------------- Kernel 4b: radix-select top-32 + softmax -> P ----------
__global__ __launch_bounds__(256)
void k_sel(float* __restrict__ QK, int* __restrict__ topk,
           float* __restrict__ abk)
{
    __shared__ int sbins[4 * 257];        // 4 wave copies, bank-staggered
    __shared__ int ired[4];
    __shared__ float fred[4];
    __shared__ unsigned skey[cK];
    __shared__ float sval[cK];
    __shared__ int sidx[cK];
    __shared__ int stopk[cK];
    __shared__ int sDig, sRem, scnt;
    __shared__ float sM;
    int tid = threadIdx.x, lane = tid & 63, wid = tid >> 6;
    int b = blockIdx.x;                  // (n*H + h)*C + c
    float* qrow = QK + (size_t)b * cS;
    float v[8]; unsigned key[8];
#pragma unroll
    for (int j = 0; j < 8; ++j) {
        float f = qrow[tid + j * 256];
        v[j] = f;
        unsigned u = __float_as_uint(f);
        key[j] = (u & 0x80000000u) ? ~u : (u | 0x80000000u);   // monotone map
    }
    if (tid == 0) { sRem = cK; scnt = 0; }
    unsigned pfx = 0;
    for (int pass = 0; pass < 4; ++pass) {
        int sh = 24 - 8 * pass;
        for (int i = tid; i < 4 * 257; i += 256) sbins[i] = 0;
        __syncthreads();
        int rem = sRem;
#pragma unroll
        for (int j = 0; j < 8; ++j) {
            bool cand = (pass == 0) || ((key[j] >> (sh + 8)) == pfx);
            if (cand) atomicAdd(&sbins[wid * 257 + ((key[j] >> sh) & 255)], 1);
        }
        __syncthreads();
        if (wid == 0) {
            int d0 = lane * 4;
            int c0 = sbins[d0] + sbins[257 + d0] + sbins[514 + d0] + sbins[771 + d0];
            int c1 = sbins[d0+1] + sbins[257+d0+1] + sbins[514+d0+1] + sbins[771+d0+1];
            int c2 = sbins[d0+2] + sbins[257+d0+2] + sbins[514+d0+2] + sbins[771+d0+2];
            int c3 = sbins[d0+3] + sbins[257+d0+3] + sbins[514+d0+3] + sbins[771+d0+3];
            int tot = c0 + c1 + c2 + c3;
            int incl = tot;                           // backward inclusive scan
#pragma unroll
            for (int off = 1; off < 64; off <<= 1) {
                int o = __shfl_down(incl, off);
                if (lane + off < 64) incl += o;
            }
            int sufHi = incl - tot;
            int G3 = sufHi, G2 = sufHi + c3, G1 = G2 + c2, G0 = G1 + c1;
            int hit = -1, hG = 0;
            if (G0 < rem && rem <= G0 + c0) { hit = d0 + 0; hG = G0; }
            if (G1 < rem && rem <= G1 + c1) { hit = d0 + 1; hG = G1; }
            if (G2 < rem && rem <= G2 + c2) { hit = d0 + 2; hG = G2; }
            if (G3 < rem && rem <= G3 + c3) { hit = d0 + 3; hG = G3; }
            unsigned long long m = __ballot(hit >= 0);
            int src = __ffsll((long long)m) - 1;
            int dsel = __shfl(hit, src);
            int Gsel = __shfl(hG, src);
            if (lane == 0) { sDig = dsel; sRem = rem - Gsel; }
        }
        __syncthreads();
        pfx = (pfx << 8) | (unsigned)sDig;
    }
    unsigned T = pfx;
    int need = sRem;
    int myT = 0;
#pragma unroll
    for (int j = 0; j < 8; ++j) myT += (key[j] == T);
#pragma unroll
    for (int off = 1; off < 64; off <<= 1) myT += __shfl_xor(myT, off);
    if (lane == 0) ired[wid] = myT;
    __syncthreads();
    int tieTot = ((ired[0] + ired[1]) + ired[2]) + ired[3];
    int tieCut = 0x7fffffff;
    if (tieTot != need) {                 // rare: pick need-th smallest tie index
        int last = -1;
        for (int t = 0; t < need; ++t) {
            int mymin = 0x7fffffff;
#pragma unroll
            for (int j = 0; j < 8; ++j) {
                int idx = tid + j * 256;
                if (key[j] == T && idx > last) mymin = min(mymin, idx);
            }
#pragma unroll
            for (int off = 1; off < 64; off <<= 1)
                mymin = min(mymin, __shfl_xor(mymin, off));
            __syncthreads();
            if (lane == 0) ired[wid] = mymin;
            __syncthreads();
            last = min(min(ired[0], ired[1]), min(ired[2], ired[3]));
        }
        tieCut = last;
    }
    __syncthreads();
    int selm = 0;
#pragma unroll
    for (int j = 0; j < 8; ++j) {
        int idx = tid + j * 256;
        bool s_ = (key[j] > T) || (key[j] == T && idx <= tieCut);
        if (s_) {
            int slot = atomicAdd(&scnt, 1);
            skey[slot] = key[j]; sidx[slot] = idx; sval[slot] = v[j];
            selm |= (1 << j);
        }
    }
    __syncthreads();
    if (tid < cK) {
        unsigned kt = skey[tid]; int it = sidx[tid];
        int rank = 0;
#pragma unroll
        for (int j = 0; j < cK; ++j)
            rank += (skey[j] > kt) || (skey[j] == kt && sidx[j] < it);
        stopk[rank] = it;
        if (rank == 0) sM = sval[tid];
    }
    __syncthreads();
    if (tid < cK) topk[(size_t)b * cK + tid] = stopk[tid];
    float M = sM;
    float e8[8]; float ps = 0.f;
#pragma unroll
    for (int j = 0; j < 8; ++j) { e8[j] = expf(0.125f * (v[j] - M)); ps += e8[j]; }
#pragma unroll
    for (int off = 1; off < 64; off <<= 1) ps += __shfl_xor(ps, off);
    if (lane == 0) fred[wid] = ps;
    __syncthreads();
    float den = ((fred[0] + fred[1]) + fred[2]) + fred[3];
    float ab = 0.f;
#pragma unroll
    for (int j = 0; j < 8; ++j) {
        float P = (selm & (1 << j)) ? 0.f : e8[j] / den;
        ab += P;
        qrow[tid + j * 256] = P;
    }
#pragma unroll
    for (int off = 1; off < 64; off <<= 1) ab += __shfl_xor(ab, off);
    __syncthreads();
    if (lane == 0) fred[wid] = ab;
    __syncthreads();
    if (tid == 0) abk[b] = ((fred[0] + fred[1]) + fred[2]) + fred[3];
}

// ---------------- Kernel 4c: Vb_g partials = P . v (split-K GEMM) --------
__global__ __launch_bounds__(256)
void k_pv(const float* __restrict__ P, const float* __restrict__ val,
          float* __restrict__ part)
{
    __shared__ float pT[64][64 + 2];       // [c_local][s_sub]
    __shared__ float vT[64][cD + 4];       // [s_sub][d]
    int tid = threadIdx.x;
    int ch = blockIdx.x & 1;
    int sk = (blockIdx.x >> 1) & 7;
    int nh = blockIdx.x >> 4;
    int h = nh % cH, n = nh / cH;
    int tx = tid & 15, ty = tid >> 4;
    float acc[4][4];
#pragma unroll
    for (int i = 0; i < 4; ++i)
#pragma unroll
        for (int j = 0; j < 4; ++j) acc[i][j] = 0.f;
    const float* pb = P + ((size_t)nh * cC + ch * 64) * cS;
    const float* vb = val + (size_t)n * cS * cH * cD + (size_t)h * cD;
    for (int sub = 0; sub < CHUNK / 64; ++sub) {
        int s0 = sk * CHUNK + sub * 64;
#pragma unroll
        for (int i = 0; i < 4; ++i) {
            int f = tid + 256 * i;
            int c = f >> 4, s4 = (f & 15) << 2;
            float4 v = *(const float4*)(pb + (size_t)c * cS + s0 + s4);
            pT[c][s4+0] = v.x; pT[c][s4+1] = v.y; pT[c][s4+2] = v.z; pT[c][s4+3] = v.w;
        }
#pragma unroll
        for (int i = 0; i < 4; ++i) {
            int f = tid + 256 * i;
            int ss = f >> 4, d4 = (f & 15) << 2;
            float4 v = *(const float4*)(vb + (size_t)(s0 + ss) * (cH * cD) + d4);
            vT[ss][d4+0] = v.x; vT[ss][d4+1] = v.y; vT[ss][d4+2] = v.z; vT[ss][d4+3] = v.w;
        }
        __syncthreads();
        for (int ss = 0; ss < 64; ++ss) {
            float pv[4];
#pragma unroll
            for (int i = 0; i < 4; ++i) pv[i] = pT[ty + 16 * i][ss];
            float4 vv = *(const float4*)&vT[ss][tx * 4];
#pragma unroll
            for (int i = 0; i < 4; ++i) {
                acc[i][0] = fmaf(pv[i], vv.x, acc[i][0]);
                acc[i][1] = fmaf(pv[i], vv.y, acc[i][1]);
                acc[i][2] = fmaf(pv[i], vv.z, acc[i][2]);
                acc[i][3] = fmaf(pv[i], vv.w, acc[i][3]);
            }
        }
        __syncthreads();
    }
    float* dst = part + (((size_t)sk * cNH + nh) * cC + ch * 64) * cD;
#pragma unroll
    for (int i = 0; i < 4; ++i) {
        float4 o; o.x = acc[i][0]; o.y = acc[i][1]; o.z = acc[i][2]; o.w = acc[i][3];
        *(float4*)(dst + (size_t)(ty + 16 * i) * cD + tx * 4) = o;
    }
}

// ---------------- Kernel 4d: reduce split-K partials ---------------------
__global__ __launch_bounds__(256)
void k_red(const float* __restrict__ part, float* __restrict__ vbg)
{
    int i = blockIdx.x * 256 + threadIdx.x;      // over 16*128*64 = 131072
    float acc = 0.f;
    for (int sk = 0; sk < SK; ++sk) acc += part[(size_t)sk * (cNH * cC * cD) + i];
    vbg[i] = acc;
}

// ---------------- Kernel 5: scheduled epilogue (8 waves + q prefetch) ----
// grid = 16 nh x 256 slots; block = 512 thr (8 waves). K half-rows in regs,
// V in LDS; per wave <=4 members with next-member q prefetch overlapping the
// compute chain. FP chains operand-identical -> bit-identical outputs.
__global__ __launch_bounds__(512)
void k_out(const float* __restrict__ q, const float* __restrict__ key,
           const float* __restrict__ val, const int* __restrict__ mlist,
           const int* __restrict__ moff, const int* __restrict__ counts,
           const float* __restrict__ abk, const float* __restrict__ vbg,
           const int* __restrict__ topk, const int* __restrict__ sched,
           float* __restrict__ out)
{
    __shared__ float vlds[cK][cD + 1];   // [k][d]: 2-way alias (free)
    __shared__ float aslds[8][cK];
    __shared__ int   st[cK];
    int tid = threadIdx.x, lane = tid & 63, wid = tid >> 6;
    int nh = blockIdx.x >> 8;
    int slot = blockIdx.x & 255;
    int item = sched[nh * SLOTS + slot];
    if (item < 0) return;                // unused slot
    int c = item & 255, part = item >> 8;
    int b = nh * cC + c;
    int h = nh % cH, n = nh / cH;
    if (tid < cK) st[tid] = topk[(size_t)b * cK + tid];
    __syncthreads();
    const float* kb = key + ((size_t)n * cS * cH + h) * cE;
    const float* vb = val + ((size_t)n * cS * cH + h) * cD;
    for (int r = wid; r < cK; r += 8)
        vlds[r][lane] = vb[(size_t)st[r] * cH * cD + lane];
    int k = lane >> 1, hh = lane & 1;
    float4 kreg[8];
    {
        const float* kr = kb + (size_t)st[k] * cH * cE + hh * 32;
#pragma unroll
        for (int j = 0; j < 8; ++j) kreg[j] = ((const float4*)kr)[j];
    }
    __syncthreads();
    int cnt = counts[b];
    int off = moff[b];
    float scale = 1.0f - abk[b];
    float vbgd = vbg[(size_t)b * cD + lane];
    float stf = (lane < cK) ? (float)st[lane] : 0.f;
    const int* ml = mlist + (size_t)nh * cL + off;
    const size_t off1 = (size_t)cN * cL * cH * cD;
    const size_t off2 = off1 + (size_t)cN * cH * cL * cK;
    int mstart = part * PARTSZ;
    int mend = min(mstart + PARTSZ, cnt);
    // my members (<=4 with 8 waves and PARTSZ=32), prefetch pipeline
    int mym[4]; int nm = 0;
    for (int m = mstart + wid; m < mend; m += 8) mym[nm++] = ml[m];
    if (nm == 0) return;                 // wave-uniform
    float4 qf[8], qn[8];
    {
        const float* q0 = q + (((size_t)n * cL + mym[0]) * cH + h) * cE + hh * 32;
#pragma unroll
        for (int j = 0; j < 8; ++j) qf[j] = ((const float4*)q0)[j];
    }
    for (int i = 0; i < nm; ++i) {       // wave-uniform trip count
        if (i + 1 < nm) {                // issue next q loads early
            const float* q1 = q + (((size_t)n * cL + mym[i + 1]) * cH + h) * cE + hh * 32;
#pragma unroll
            for (int j = 0; j < 8; ++j) qn[j] = ((const float4*)q1)[j];
        }
        int l = mym[i];
        // half-dot: ascending e within my half, register operands only
        float partial = 0.f;
#pragma unroll
        for (int j = 0; j < 8; ++j) {
            partial = fmaf(qf[j].x, kreg[j].x, partial);
            partial = fmaf(qf[j].y, kreg[j].y, partial);
            partial = fmaf(qf[j].z, kreg[j].z, partial);
            partial = fmaf(qf[j].w, kreg[j].w, partial);
        }
        float qk = partial + __shfl_xor(partial, 1);   // low half + high half
        float M = qk;
#pragma unroll
        for (int o = 2; o < 64; o <<= 1) M = fmaxf(M, __shfl_xor(M, o));
        float ev = expf(0.125f * (qk - M));
        float den = ev;
#pragma unroll
        for (int o = 2; o < 64; o <<= 1) den += __shfl_xor(den, o);
        float as_ = (ev / den) * scale;                // A_s for my k
        if (!hh) aslds[wid][k] = as_;
        float acc = 0.f;
#pragma unroll
        for (int j = 0; j < cK; ++j)
            acc = fmaf(aslds[wid][j], vlds[j][lane], acc);
        acc += vbgd;
        int qidx = nh * cL + l;
        out[(((size_t)n * cL + l) * cH + h) * cD + lane] = acc;   // (N,L,H,D)
        if (lane < cK) {
            out[off1 + (size_t)qidx * cK + lane] = stf;           // sparse_index
            out[off2 + (size_t)qidx * cK + lane] = aslds[wid][lane]; // A_topk
        }
#pragma unroll
        for (int j = 0; j < 8; ++j) qf[j] = qn[j];
    }
}

// ---------------- launch -------------------------------------------------
extern "C" void kernel_launch(void* const* d_in, const int* in_sizes, int n_in,
                              void* d_out, int out_size, void* d_ws, size_t ws_size,
                              hipStream_t stream)
{
    (void)in_sizes; (void)n_in; (void)out_size; (void)ws_size;
    const float* q      = (const float*)d_in[0];
    const float* key    = (const float*)d_in[1];
    const float* val    = (const float*)d_in[2];
    const float* planes = (const float*)d_in[3];
    char* w = (char*)d_ws;
    unsigned int* bits = (unsigned int*)w;  w += (size_t)cN * cH * cL * 4;
    int*   cl     = (int*)w;                w += (size_t)cN * cH * cL * 4;
    int*   counts = (int*)w;                w += (size_t)cN * cH * cC * 4;
    float* abk    = (float*)w;              w += (size_t)cN * cH * cC * 4;
    float* Qg     = (float*)w;              w += (size_t)cN * cH * cC * cE * 4;
    float* vbg    = (float*)w;              w += (size_t)cN * cH * cC * cD * 4;
    int*   topkp  = (int*)w;                w += (size_t)cN * cH * cC * cK * 4;
    float* QK     = (float*)w;              w += (size_t)cNH * cC * cS * 4;      // 16 MB
    float* part   = (float*)w;              w += (size_t)SK * cNH * cC * cD * 4; // 4 MB
    int*   ghist  = (int*)w;                w += (size_t)NBUF * cNH * HW * 4;    // 2.97 MB
    unsigned int* cents = (unsigned int*)w; w += (size_t)NBUF * cNH * cC * 4;    // 90 KB
    int*   pcounts= (int*)w;                w += (size_t)cNH * NT * cC * 4;      // 128 KB
    int*   mlist  = (int*)w;                w += (size_t)cNH * cL * 4;           // 128 KB
    int*   moff   = (int*)w;                w += (size_t)cNH * cC * 4;           // 8 KB
    int*   sched  = (int*)w;                w += (size_t)cNH * SLOTS * 4;        // 16 KB
    float* out = (float*)d_out;

    k_bits <<<(cN * cH * cL) / 256, 256, 0, stream>>>(q, planes, bits, ghist);
    for (int it = 0; it <= cIT; ++it)
        k_lloyd <<<cNH * NT, 128, 0, stream>>>(bits, ghist, cents, cl, pcounts, it);
    k_rank <<<cNH * NT, 128, 0, stream>>>(cl, pcounts, counts, moff, sched, mlist);
    k_qg     <<<cNH * cC, 64, 0, stream>>>(q, mlist, moff, counts, Qg);
    k_qk_gemm<<<cNH * 16, 256, 0, stream>>>(key, Qg, QK);
    k_sel    <<<cNH * cC, 256, 0, stream>>>(QK, topkp, abk);
    k_pv     <<<cNH * SK * 2, 256, 0, stream>>>(QK, val, part);
    k_red    <<<(cNH * cC * cD) / 256, 256, 0, stream>>>(part, vbg);
    k_out    <<<cNH * SLOTS, 512, 0, stream>>>(q, key, val, mlist, moff, counts,
                                               abk, vbg, topkp, sched, out);
}

// Round 17
// 325.351 us; speedup vs baseline: 1.0996x; 1.0996x over previous
//
#include <hip/hip_runtime.h>
#include <math.h>

constexpr int cN = 2, cH = 8, cL = 2048, cS = 2048, cE = 64, cD = 64;
constexpr int cC = 128, cK = 32, cB = 32, cIT = 10;
constexpr int cNH = cN * cH;          // 16
constexpr int SK = 8;                 // split-K factor for PV
constexpr int CHUNK = cS / SK;        // 256 s per split
constexpr int NT = 16;                // point tiles per nh (128 points each)
constexpr int HW = cC * 33;           // hist words: sbs[128][32] + scnt[128] = 4224
constexpr int PARTSZ = 16;            // members per k_out work item
constexpr int SLOTS = 256;            // schedule slots per nh (max 256 used)
constexpr int NBUF = cIT + 1;         // 11 ghist buffers (one per iteration)
// TEMP = 1/sqrt(64) = 0.125 exactly

// ---------------- Kernel 1: LSH bits + zero ghist ------------------------
__global__ __launch_bounds__(256)
void k_bits(const float* __restrict__ q, const float* __restrict__ planes,
            unsigned int* __restrict__ bits, int* __restrict__ ghist)
{
    __shared__ float pl[cB * 68];               // padded rows, 16B-aligned
    int tid = threadIdx.x;
    for (int i = tid; i < cB * (cE + 1); i += 256) {
        int b = i / 65, e = i % 65;
        pl[b * 68 + e] = planes[i];
    }
    {   // zero my slice of the 11 global hist buffers
        const int ZS = NBUF * cNH * HW / 128;   // 5808 (grid = 128 blocks)
        for (int i = tid; i < ZS; i += 256) ghist[(size_t)blockIdx.x * ZS + i] = 0;
    }
    __syncthreads();
    int idx = blockIdx.x * 256 + tid;           // (n*H + h)*L + l
    int l = idx % cL, h = (idx / cL) % cH, n = idx / (cL * cH);
    const float* qr = q + (((size_t)n * cL + l) * cH + h) * cE;
    float qv[cE];
#pragma unroll
    for (int e4 = 0; e4 < cE / 4; ++e4) {
        float4 f = ((const float4*)qr)[e4];
        qv[4*e4+0] = f.x; qv[4*e4+1] = f.y; qv[4*e4+2] = f.z; qv[4*e4+3] = f.w;
    }
    unsigned int w = 0;
    for (int b = 0; b < cB; ++b) {
        const float4* pr = (const float4*)(pl + b * 68);
        float acc = 0.f;
#pragma unroll
        for (int e4 = 0; e4 < cE / 4; ++e4) {
            float4 f = pr[e4];
            acc = fmaf(qv[4*e4+0], f.x, acc);
            acc = fmaf(qv[4*e4+1], f.y, acc);
            acc = fmaf(qv[4*e4+2], f.z, acc);
            acc = fmaf(qv[4*e4+3], f.w, acc);
        }
        acc += pl[b * 68 + 64];
        if (acc > 0.f) w |= (1u << b);
    }
    bits[idx] = w;
}

// ---------------- Kernel 2: one Lloyd iteration (update fused in) --------
// grid = 16 nh x 16 tiles = 256 blocks x 128 thr (1 point/thread).
// scb_it recomputed locally (cents[it-1] + ghist[it-1], integer-exact);
// tile 0 writes cents[it]. Last call (it==cIT) writes cl + pcounts.
__global__ __launch_bounds__(128)
void k_lloyd(const unsigned int* __restrict__ bits, int* __restrict__ ghist,
             unsigned int* __restrict__ cents, int* __restrict__ cl,
             int* __restrict__ pcounts, int it)
{
    __shared__ unsigned int scb[cC] __attribute__((aligned(16)));
    __shared__ int hist[HW];
    int tid = threadIdx.x, lane = tid & 63;
    int tile = blockIdx.x & (NT - 1), nh = blockIdx.x / NT;
    // ---- reconstruct scb_it (identical in every block of this nh) -------
    if (it == 0) {
        if (tid < cC) {
            // linspace(0,L-1,C).astype(int32): floor(c*2047/127), endpoint exact
            int i0 = (int)(((double)tid * 2047.0) / 127.0);
            scb[tid] = bits[(size_t)nh * cL + i0];
        }
    } else {
        const unsigned int* cp = cents + (size_t)(it - 1) * cNH * cC + nh * cC;
        const int* gb = ghist + (size_t)((it - 1) * cNH + nh) * HW;
        if (tid < cC) {
            unsigned int oldc = cp[tid];
            int cnt = gb[4096 + tid];
            if (cnt > 0) {
                unsigned int nw = 0;
#pragma unroll
                for (int b = 0; b < cB; ++b)
                    if (2 * gb[tid * 32 + b] > cnt) nw |= (1u << b);
                oldc = nw;
            }
            scb[tid] = oldc;
        }
    }
    for (int i = tid; i < HW; i += 128) hist[i] = 0;
    int l = tile * 128 + tid;
    unsigned int w = bits[(size_t)nh * cL + l];
    // per-lane bit ballots (lane b&31 keeps bit b of this wave's points)
    unsigned long long mymb = 0ull;
#pragma unroll
    for (int b = 0; b < cB; ++b) {
        unsigned long long m = __ballot((w >> b) & 1u);
        if ((lane & 31) == b) mymb = m;
    }
    __syncthreads();
    if (tile == 0 && it < cIT && tid < cC)
        cents[(size_t)it * cNH * cC + nh * cC + tid] = scb[tid];
    // ---- assignment: packed (hamming<<8)|c min; tie -> lowest c ---------
    const uint4* scb4 = (const uint4*)scb;
    int best = 0x7fffffff;
    for (int c4 = 0; c4 < cC / 4; ++c4) {
        uint4 cb = scb4[c4];
        int c = c4 * 4;
        best = min(best, (__popc(w ^ cb.x) << 8) | c);
        best = min(best, (__popc(w ^ cb.y) << 8) | (c + 1));
        best = min(best, (__popc(w ^ cb.z) << 8) | (c + 2));
        best = min(best, (__popc(w ^ cb.w) << 8) | (c + 3));
    }
    int bc = best & 255;
    if (it == cIT) cl[(size_t)nh * cL + l] = bc;
    // ---- wave-aggregated histogram into LDS -----------------------------
    for (int c = 0; c < cC; ++c) {
        unsigned long long m = __ballot(bc == c);
        if (m) {
            if (lane < cB) {
                int contrib = __popcll(m & mymb);
                if (contrib) atomicAdd(&hist[c * 32 + lane], contrib);
            }
            if (lane == 63) atomicAdd(&hist[4096 + c], __popcll(m));
        }
    }
    __syncthreads();
    // ---- flush nonzero to this iteration's global buffer ----------------
    int* gb = ghist + (size_t)(it * cNH + nh) * HW;
    for (int i = tid; i < HW; i += 128) {
        int v = hist[i];
        if (v) atomicAdd(&gb[i], v);
    }
    if (it == cIT && tid < cC)
        pcounts[(nh * NT + tile) * cC + tid] = hist[4096 + tid];
}

// ---------------- Kernel 2c: rank + (tile0) counts/moff/sched ------------
// grid = 16 nh x 16 tiles = 256 blocks x 128 thr (1 point/thread).
// Each block recomputes counts/moff locally from pcounts (integer-exact).
__global__ __launch_bounds__(128)
void k_rank(const int* __restrict__ cl, const int* __restrict__ pcounts,
            int* __restrict__ counts, int* __restrict__ moff,
            int* __restrict__ sched, int* __restrict__ mlist)
{
    __shared__ int pre[cC];       // exclusive prefix of full counts
    __shared__ int scn[cC];       // full counts
    __shared__ int sbefore[cC];   // sum of pcounts for tiles < mine
    __shared__ int wcnt0[cC];
    int tid = threadIdx.x, lane = tid & 63, wid = tid >> 6;
    int tile = blockIdx.x & (NT - 1), nh = blockIdx.x / NT;
    if (tid < cC) {
        int tot = 0, bef = 0;
        for (int t = 0; t < NT; ++t) {
            int v = pcounts[(nh * NT + t) * cC + tid];
            if (t < tile) bef += v;
            tot += v;
        }
        scn[tid] = tot;
        sbefore[tid] = bef;
    }
    __syncthreads();
    if (tid == 0) {
        int run = 0;
        for (int i = 0; i < cC; ++i) { pre[i] = run; run += scn[i]; }
    }
    __syncthreads();
    if (tile == 0) {                              // block-uniform branch
        if (tid < cC) {
            counts[nh * cC + tid] = scn[tid];
            moff[nh * cC + tid] = pre[tid];
        }
        sched[nh * SLOTS + tid] = -1;
        sched[nh * SLOTS + 128 + tid] = -1;
        __syncthreads();
        if (tid == 0) {
            int slot = 0;
            for (int i = 0; i < cC; ++i) {
                int np = (scn[i] + PARTSZ - 1) / PARTSZ;
                for (int p = 0; p < np; ++p)
                    sched[nh * SLOTS + slot++] = i | (p << 8);
            }
        }
    }
    int l = tile * 128 + tid;
    int bc = cl[(size_t)nh * cL + l];
    unsigned long long ltmask = (1ull << lane) - 1ull;
    int myrank = 0;
    for (int c = 0; c < cC; ++c) {
        unsigned long long m = __ballot(bc == c);
        if (wid == 0 && lane == 0) wcnt0[c] = __popcll(m);
        if (bc == c) myrank = __popcll(m & ltmask);
    }
    __syncthreads();
    int off = pre[bc] + sbefore[bc] + myrank + (wid == 1 ? wcnt0[bc] : 0);
    mlist[(size_t)nh * cL + off] = l;
}

// ---------------- Kernel 3: cluster-mean queries Qg ----------------------
// one block (64 lanes = e) per (nh,c); strict ascending-l chain (bit-exact)
__global__ __launch_bounds__(64)
void k_qg(const float* __restrict__ q, const int* __restrict__ mlist,
          const int* __restrict__ moff, const int* __restrict__ counts,
          float* __restrict__ Qg)
{
    int b = blockIdx.x;                 // nh*cC + c
    int nh = b >> 7;
    int h = nh % cH, n = nh / cH;
    int lane = threadIdx.x;
    int off = moff[b];
    int cnt = counts[b];
    const int* ml = mlist + (size_t)nh * cL + off;
    const float* qb = q + ((size_t)n * cL * cH + h) * cE + lane;
    float acc = 0.f;
    int j = 0;
    for (; j + 4 <= cnt; j += 4) {
        int i0 = ml[j], i1 = ml[j + 1], i2 = ml[j + 2], i3 = ml[j + 3];
        float v0 = qb[(size_t)i0 * cH * cE];
        float v1 = qb[(size_t)i1 * cH * cE];
        float v2 = qb[(size_t)i2 * cH * cE];
        float v3 = qb[(size_t)i3 * cH * cE];
        acc += v0; acc += v1; acc += v2; acc += v3;    // in-order chain
    }
    for (; j < cnt; ++j) acc += qb[(size_t)ml[j] * cH * cE];
    float cs = (float)(cnt > 0 ? cnt : 1);
    Qg[(size_t)b * cE + lane] = acc / cs;
}

// ---------------- Kernel 4a: QK = Qg . k^T  (tiled GEMM, exact chains) ---
__global__ __launch_bounds__(256)
void k_qk_gemm(const float* __restrict__ key, const float* __restrict__ Qg,
               float* __restrict__ QK)
{
    __shared__ float qgT[cE][cC + 2];      // [e][c]
    __shared__ float kT[cE][128 + 2];      // [e][s_local]
    int tid = threadIdx.x;
    int bs = blockIdx.x & 15;              // s-tile
    int nh = blockIdx.x >> 4;
    int h = nh % cH, n = nh / cH;
    const float4* qsrc = (const float4*)(Qg + (size_t)nh * cC * cE);
#pragma unroll
    for (int i = 0; i < 8; ++i) {
        int f = tid + 256 * i;
        int c = f >> 4, e4 = (f & 15) << 2;
        float4 v = qsrc[f];
        qgT[e4+0][c] = v.x; qgT[e4+1][c] = v.y; qgT[e4+2][c] = v.z; qgT[e4+3][c] = v.w;
    }
    const float* kb = key + (size_t)n * cS * cH * cE + (size_t)h * cE;
    int s0 = bs * 128;
#pragma unroll
    for (int i = 0; i < 8; ++i) {
        int f = tid + 256 * i;
        int s = f >> 4, e4 = (f & 15) << 2;
        float4 v = *(const float4*)(kb + (size_t)(s0 + s) * (cH * cE) + e4);
        kT[e4+0][s] = v.x; kT[e4+1][s] = v.y; kT[e4+2][s] = v.z; kT[e4+3][s] = v.w;
    }
    __syncthreads();
    int tx = tid & 15, ty = tid >> 4;
    float acc[8][8];
#pragma unroll
    for (int i = 0; i < 8; ++i)
#pragma unroll
        for (int j = 0; j < 8; ++j) acc[i][j] = 0.f;
    for (int e = 0; e < cE; ++e) {
        float qv[8], kv[8];
#pragma unroll
        for (int i = 0; i < 8; ++i) qv[i] = qgT[e][ty + 16 * i];
#pragma unroll
        for (int j = 0; j < 8; ++j) kv[j] = kT[e][tx + 16 * j];
#pragma unroll
        for (int i = 0; i < 8; ++i)
#pragma unroll
            for (int j = 0; j < 8; ++j)
                acc[i][j] = fmaf(qv[i], kv[j], acc[i][j]);   // ascending-e chain
    }
    float* dst = QK + (size_t)nh * cC * cS + s0;
#pragma unroll
    for (int i = 0; i < 8; ++i)
#pragma unroll
        for (int j = 0; j < 8; ++j)
            dst[(size_t)(ty + 16 * i) * cS + tx + 16 * j] = acc[i][j];
}

// ---------------- Kernel 4b: radix-select top-32 + softmax -> P ----------
__global__ __launch_bounds__(256)
void k_sel(float* __restrict__ QK, int* __restrict__ topk,
           float* __restrict__ abk)
{
    __shared__ int sbins[4 * 257];        // 4 wave copies, bank-staggered
    __shared__ int ired[4];
    __shared__ float fred[4];
    __shared__ unsigned skey[cK];
    __shared__ float sval[cK];
    __shared__ int sidx[cK];
    __shared__ int stopk[cK];
    __shared__ int sDig, sRem, scnt;
    __shared__ float sM;
    int tid = threadIdx.x, lane = tid & 63, wid = tid >> 6;
    int b = blockIdx.x;                  // (n*H + h)*C + c
    float* qrow = QK + (size_t)b * cS;
    float v[8]; unsigned key[8];
#pragma unroll
    for (int j = 0; j < 8; ++j) {
        float f = qrow[tid + j * 256];
        v[j] = f;
        unsigned u = __float_as_uint(f);
        key[j] = (u & 0x80000000u) ? ~u : (u | 0x80000000u);   // monotone map
    }
    if (tid == 0) { sRem = cK; scnt = 0; }
    unsigned pfx = 0;
    for (int pass = 0; pass < 4; ++pass) {
        int sh = 24 - 8 * pass;
        for (int i = tid; i < 4 * 257; i += 256) sbins[i] = 0;
        __syncthreads();
        int rem = sRem;
#pragma unroll
        for (int j = 0; j < 8; ++j) {
            bool cand = (pass == 0) || ((key[j] >> (sh + 8)) == pfx);
            if (cand) atomicAdd(&sbins[wid * 257 + ((key[j] >> sh) & 255)], 1);
        }
        __syncthreads();
        if (wid == 0) {
            int d0 = lane * 4;
            int c0 = sbins[d0] + sbins[257 + d0] + sbins[514 + d0] + sbins[771 + d0];
            int c1 = sbins[d0+1] + sbins[257+d0+1] + sbins[514+d0+1] + sbins[771+d0+1];
            int c2 = sbins[d0+2] + sbins[257+d0+2] + sbins[514+d0+2] + sbins[771+d0+2];
            int c3 = sbins[d0+3] + sbins[257+d0+3] + sbins[514+d0+3] + sbins[771+d0+3];
            int tot = c0 + c1 + c2 + c3;
            int incl = tot;                           // backward inclusive scan
#pragma unroll
            for (int off = 1; off < 64; off <<= 1) {
                int o = __shfl_down(incl, off);
                if (lane + off < 64) incl += o;
            }
            int sufHi = incl - tot;
            int G3 = sufHi, G2 = sufHi + c3, G1 = G2 + c2, G0 = G1 + c1;
            int hit = -1, hG = 0;
            if (G0 < rem && rem <= G0 + c0) { hit = d0 + 0; hG = G0; }
            if (G1 < rem && rem <= G1 + c1) { hit = d0 + 1; hG = G1; }
            if (G2 < rem && rem <= G2 + c2) { hit = d0 + 2; hG = G2; }
            if (G3 < rem && rem <= G3 + c3) { hit = d0 + 3; hG = G3; }
            unsigned long long m = __ballot(hit >= 0);
            int src = __ffsll((long long)m) - 1;
            int dsel = __shfl(hit, src);
            int Gsel = __shfl(hG, src);
            if (lane == 0) { sDig = dsel; sRem = rem - Gsel; }
        }
        __syncthreads();
        pfx = (pfx << 8) | (unsigned)sDig;
    }
    unsigned T = pfx;
    int need = sRem;
    int myT = 0;
#pragma unroll
    for (int j = 0; j < 8; ++j) myT += (key[j] == T);
#pragma unroll
    for (int off = 1; off < 64; off <<= 1) myT += __shfl_xor(myT, off);
    if (lane == 0) ired[wid] = myT;
    __syncthreads();
    int tieTot = ((ired[0] + ired[1]) + ired[2]) + ired[3];
    int tieCut = 0x7fffffff;
    if (tieTot != need) {                 // rare: pick need-th smallest tie index
        int last = -1;
        for (int t = 0; t < need; ++t) {
            int mymin = 0x7fffffff;
#pragma unroll
            for (int j = 0; j < 8; ++j) {
                int idx = tid + j * 256;
                if (key[j] == T && idx > last) mymin = min(mymin, idx);
            }
#pragma unroll
            for (int off = 1; off < 64; off <<= 1)
                mymin = min(mymin, __shfl_xor(mymin, off));
            __syncthreads();
            if (lane == 0) ired[wid] = mymin;
            __syncthreads();
            last = min(min(ired[0], ired[1]), min(ired[2], ired[3]));
        }
        tieCut = last;
    }
    __syncthreads();
    int selm = 0;
#pragma unroll
    for (int j = 0; j < 8; ++j) {
        int idx = tid + j * 256;
        bool s_ = (key[j] > T) || (key[j] == T && idx <= tieCut);
        if (s_) {
            int slot = atomicAdd(&scnt, 1);
            skey[slot] = key[j]; sidx[slot] = idx; sval[slot] = v[j];
            selm |= (1 << j);
        }
    }
    __syncthreads();
    if (tid < cK) {
        unsigned kt = skey[tid]; int it = sidx[tid];
        int rank = 0;
#pragma unroll
        for (int j = 0; j < cK; ++j)
            rank += (skey[j] > kt) || (skey[j] == kt && sidx[j] < it);
        stopk[rank] = it;
        if (rank == 0) sM = sval[tid];
    }
    __syncthreads();
    if (tid < cK) topk[(size_t)b * cK + tid] = stopk[tid];
    float M = sM;
    float e8[8]; float ps = 0.f;
#pragma unroll
    for (int j = 0; j < 8; ++j) { e8[j] = expf(0.125f * (v[j] - M)); ps += e8[j]; }
#pragma unroll
    for (int off = 1; off < 64; off <<= 1) ps += __shfl_xor(ps, off);
    if (lane == 0) fred[wid] = ps;
    __syncthreads();
    float den = ((fred[0] + fred[1]) + fred[2]) + fred[3];
    float ab = 0.f;
#pragma unroll
    for (int j = 0; j < 8; ++j) {
        float P = (selm & (1 << j)) ? 0.f : e8[j] / den;
        ab += P;
        qrow[tid + j * 256] = P;
    }
#pragma unroll
    for (int off = 1; off < 64; off <<= 1) ab += __shfl_xor(ab, off);
    __syncthreads();
    if (lane == 0) fred[wid] = ab;
    __syncthreads();
    if (tid == 0) abk[b] = ((fred[0] + fred[1]) + fred[2]) + fred[3];
}

// ---------------- Kernel 4c: Vb_g partials = P . v (split-K GEMM) --------
__global__ __launch_bounds__(256)
void k_pv(const float* __restrict__ P, const float* __restrict__ val,
          float* __restrict__ part)
{
    __shared__ float pT[64][64 + 2];       // [c_local][s_sub]
    __shared__ float vT[64][cD + 4];       // [s_sub][d]
    int tid = threadIdx.x;
    int ch = blockIdx.x & 1;
    int sk = (blockIdx.x >> 1) & 7;
    int nh = blockIdx.x >> 4;
    int h = nh % cH, n = nh / cH;
    int tx = tid & 15, ty = tid >> 4;
    float acc[4][4];
#pragma unroll
    for (int i = 0; i < 4; ++i)
#pragma unroll
        for (int j = 0; j < 4; ++j) acc[i][j] = 0.f;
    const float* pb = P + ((size_t)nh * cC + ch * 64) * cS;
    const float* vb = val + (size_t)n * cS * cH * cD + (size_t)h * cD;
    for (int sub = 0; sub < CHUNK / 64; ++sub) {
        int s0 = sk * CHUNK + sub * 64;
#pragma unroll
        for (int i = 0; i < 4; ++i) {
            int f = tid + 256 * i;
            int c = f >> 4, s4 = (f & 15) << 2;
            float4 v = *(const float4*)(pb + (size_t)c * cS + s0 + s4);
            pT[c][s4+0] = v.x; pT[c][s4+1] = v.y; pT[c][s4+2] = v.z; pT[c][s4+3] = v.w;
        }
#pragma unroll
        for (int i = 0; i < 4; ++i) {
            int f = tid + 256 * i;
            int ss = f >> 4, d4 = (f & 15) << 2;
            float4 v = *(const float4*)(vb + (size_t)(s0 + ss) * (cH * cD) + d4);
            vT[ss][d4+0] = v.x; vT[ss][d4+1] = v.y; vT[ss][d4+2] = v.z; vT[ss][d4+3] = v.w;
        }
        __syncthreads();
        for (int ss = 0; ss < 64; ++ss) {
            float pv[4];
#pragma unroll
            for (int i = 0; i < 4; ++i) pv[i] = pT[ty + 16 * i][ss];
            float4 vv = *(const float4*)&vT[ss][tx * 4];
#pragma unroll
            for (int i = 0; i < 4; ++i) {
                acc[i][0] = fmaf(pv[i], vv.x, acc[i][0]);
                acc[i][1] = fmaf(pv[i], vv.y, acc[i][1]);
                acc[i][2] = fmaf(pv[i], vv.z, acc[i][2]);
                acc[i][3] = fmaf(pv[i], vv.w, acc[i][3]);
            }
        }
        __syncthreads();
    }
    float* dst = part + (((size_t)sk * cNH + nh) * cC + ch * 64) * cD;
#pragma unroll
    for (int i = 0; i < 4; ++i) {
        float4 o; o.x = acc[i][0]; o.y = acc[i][1]; o.z = acc[i][2]; o.w = acc[i][3];
        *(float4*)(dst + (size_t)(ty + 16 * i) * cD + tx * 4) = o;
    }
}

// ---------------- Kernel 5: scheduled per-cluster epilogue ---------------
// grid = 16 nh x 256 slots; block = 256 thr (4 waves). K half-rows in regs,
// V in LDS; per wave <=4 members (PARTSZ=16). vbg summed inline from the 8
// split-K partials (ascending sk, same chain as the old k_red -> bit-exact).
__global__ __launch_bounds__(256)
void k_out(const float* __restrict__ q, const float* __restrict__ key,
           const float* __restrict__ val, const int* __restrict__ mlist,
           const int* __restrict__ moff, const int* __restrict__ counts,
           const float* __restrict__ abk, const float* __restrict__ part,
           const int* __restrict__ topk, const int* __restrict__ sched,
           float* __restrict__ out)
{
    __shared__ float vlds[cK][cD + 1];   // [k][d]: 2-way alias (free)
    __shared__ float aslds[4][cK];
    __shared__ int   st[cK];
    int tid = threadIdx.x, lane = tid & 63, wid = tid >> 6;
    int nh = blockIdx.x >> 8;
    int slot = blockIdx.x & 255;
    int item = sched[nh * SLOTS + slot];
    if (item < 0) return;                // unused slot
    int c = item & 255, part_i = item >> 8;
    int b = nh * cC + c;
    int h = nh % cH, n = nh / cH;
    if (tid < cK) st[tid] = topk[(size_t)b * cK + tid];
    __syncthreads();
    const float* kb = key + ((size_t)n * cS * cH + h) * cE;
    const float* vb = val + ((size_t)n * cS * cH + h) * cD;
    for (int r = wid; r < cK; r += 4)
        vlds[r][lane] = vb[(size_t)st[r] * cH * cD + lane];
    int k = lane >> 1, hh = lane & 1;
    float4 kreg[8];
    {
        const float* kr = kb + (size_t)st[k] * cH * cE + hh * 32;
#pragma unroll
        for (int j = 0; j < 8; ++j) kreg[j] = ((const float4*)kr)[j];
    }
    // vbg = ascending-sk sum of split-K partials (same chain as old k_red)
    float vbgd = 0.f;
    {
        const float* pp = part + (size_t)b * cD + lane;
#pragma unroll
        for (int sk = 0; sk < SK; ++sk)
            vbgd += pp[(size_t)sk * (cNH * cC * cD)];
    }
    __syncthreads();
    int cnt = counts[b];
    int off = moff[b];
    float scale = 1.0f - abk[b];
    float stf = (lane < cK) ? (float)st[lane] : 0.f;
    const int* ml = mlist + (size_t)nh * cL + off;
    const size_t off1 = (size_t)cN * cL * cH * cD;
    const size_t off2 = off1 + (size_t)cN * cH * cL * cK;
    int mstart = part_i * PARTSZ;
    int mend = min(mstart + PARTSZ, cnt);
    for (int m = mstart + wid; m < mend; m += 4) {   // wave-uniform loop
        int l = ml[m];
        const float* qrow = q + (((size_t)n * cL + l) * cH + h) * cE + hh * 32;
        float4 qf[8];
#pragma unroll
        for (int j = 0; j < 8; ++j) qf[j] = ((const float4*)qrow)[j];
        float partial = 0.f;
#pragma unroll
        for (int j = 0; j < 8; ++j) {
            partial = fmaf(qf[j].x, kreg[j].x, partial);
            partial = fmaf(qf[j].y, kreg[j].y, partial);
            partial = fmaf(qf[j].z, kreg[j].z, partial);
            partial = fmaf(qf[j].w, kreg[j].w, partial);
        }
        float qk = partial + __shfl_xor(partial, 1);   // low half + high half
        float M = qk;
#pragma unroll
        for (int o = 2; o < 64; o <<= 1) M = fmaxf(M, __shfl_xor(M, o));
        float ev = expf(0.125f * (qk - M));
        float den = ev;
#pragma unroll
        for (int o = 2; o < 64; o <<= 1) den += __shfl_xor(den, o);
        float as_ = (ev / den) * scale;                // A_s for my k
        if (!hh) aslds[wid][k] = as_;
        float acc = 0.f;
#pragma unroll
        for (int j = 0; j < cK; ++j)
            acc = fmaf(aslds[wid][j], vlds[j][lane], acc);
        acc += vbgd;
        int qidx = nh * cL + l;
        out[(((size_t)n * cL + l) * cH + h) * cD + lane] = acc;   // (N,L,H,D)
        if (lane < cK) {
            out[off1 + (size_t)qidx * cK + lane] = stf;           // sparse_index
            out[off2 + (size_t)qidx * cK + lane] = aslds[wid][lane]; // A_topk
        }
    }
}

// ---------------- launch -------------------------------------------------
extern "C" void kernel_launch(void* const* d_in, const int* in_sizes, int n_in,
                              void* d_out, int out_size, void* d_ws, size_t ws_size,
                              hipStream_t stream)
{
    (void)in_sizes; (void)n_in; (void)out_size; (void)ws_size;
    const float* q      = (const float*)d_in[0];
    const float* key    = (const float*)d_in[1];
    const float* val    = (const float*)d_in[2];
    const float* planes = (const float*)d_in[3];
    char* w = (char*)d_ws;
    unsigned int* bits = (unsigned int*)w;  w += (size_t)cN * cH * cL * 4;
    int*   cl     = (int*)w;                w += (size_t)cN * cH * cL * 4;
    int*   counts = (int*)w;                w += (size_t)cN * cH * cC * 4;
    float* abk    = (float*)w;              w += (size_t)cN * cH * cC * 4;
    float* Qg     = (float*)w;              w += (size_t)cN * cH * cC * cE * 4;
    int*   topkp  = (int*)w;                w += (size_t)cN * cH * cC * cK * 4;
    float* QK     = (float*)w;              w += (size_t)cNH * cC * cS * 4;      // 16 MB
    float* part   = (float*)w;              w += (size_t)SK * cNH * cC * cD * 4; // 4 MB
    int*   ghist  = (int*)w;                w += (size_t)NBUF * cNH * HW * 4;    // 2.97 MB
    unsigned int* cents = (unsigned int*)w; w += (size_t)NBUF * cNH * cC * 4;    // 90 KB
    int*   pcounts= (int*)w;                w += (size_t)cNH * NT * cC * 4;      // 128 KB
    int*   mlist  = (int*)w;                w += (size_t)cNH * cL * 4;           // 128 KB
    int*   moff   = (int*)w;                w += (size_t)cNH * cC * 4;           // 8 KB
    int*   sched  = (int*)w;                w += (size_t)cNH * SLOTS * 4;        // 16 KB
    float* out = (float*)d_out;

    k_bits <<<(cN * cH * cL) / 256, 256, 0, stream>>>(q, planes, bits, ghist);
    for (int it = 0; it <= cIT; ++it)
        k_lloyd <<<cNH * NT, 128, 0, stream>>>(bits, ghist, cents, cl, pcounts, it);
    k_rank <<<cNH * NT, 128, 0, stream>>>(cl, pcounts, counts, moff, sched, mlist);
    k_qg     <<<cNH * cC, 64, 0, stream>>>(q, mlist, moff, counts, Qg);
    k_qk_gemm<<<cNH * 16, 256, 0, stream>>>(key, Qg, QK);
    k_sel    <<<cNH * cC, 256, 0, stream>>>(QK, topkp, abk);
    k_pv     <<<cNH * SK * 2, 256, 0, stream>>>(QK, val, part);
    k_out    <<<cNH * SLOTS, 256, 0, stream>>>(q, key, val, mlist, moff, counts,
                                               abk, part, topkp, sched, out);
}

// Round 18
// 309.687 us; speedup vs baseline: 1.1552x; 1.0506x over previous
//
#include <hip/hip_runtime.h>
#include <math.h>

constexpr int cN = 2, cH = 8, cL = 2048, cS = 2048, cE = 64, cD = 64;
constexpr int cC = 128, cK = 32, cB = 32, cIT = 10;
constexpr int cNH = cN * cH;          // 16
constexpr int SK = 8;                 // split-K factor for PV
constexpr int CHUNK = cS / SK;        // 256 s per split
constexpr int NT = 16;                // point tiles per nh (128 points each)
constexpr int HW = cC * 33;           // hist words: sbs[128][32] + scnt[128] = 4224
constexpr int PARTSZ = 16;            // members per k_out work item
constexpr int SLOTS = 256;            // schedule slots per nh (max 256 used)
constexpr int NBUF = cIT + 1;         // 11 ghist buffers (one per iteration)
// TEMP = 1/sqrt(64) = 0.125 exactly

// ---------------- Kernel 1: LSH bits + zero ghist ------------------------
__global__ __launch_bounds__(256)
void k_bits(const float* __restrict__ q, const float* __restrict__ planes,
            unsigned int* __restrict__ bits, int* __restrict__ ghist)
{
    __shared__ float pl[cB * 68];               // padded rows, 16B-aligned
    int tid = threadIdx.x;
    for (int i = tid; i < cB * (cE + 1); i += 256) {
        int b = i / 65, e = i % 65;
        pl[b * 68 + e] = planes[i];
    }
    {   // zero my slice of the 11 global hist buffers
        const int ZS = NBUF * cNH * HW / 128;   // 5808 (grid = 128 blocks)
        for (int i = tid; i < ZS; i += 256) ghist[(size_t)blockIdx.x * ZS + i] = 0;
    }
    __syncthreads();
    int idx = blockIdx.x * 256 + tid;           // (n*H + h)*L + l
    int l = idx % cL, h = (idx / cL) % cH, n = idx / (cL * cH);
    const float* qr = q + (((size_t)n * cL + l) * cH + h) * cE;
    float qv[cE];
#pragma unroll
    for (int e4 = 0; e4 < cE / 4; ++e4) {
        float4 f = ((const float4*)qr)[e4];
        qv[4*e4+0] = f.x; qv[4*e4+1] = f.y; qv[4*e4+2] = f.z; qv[4*e4+3] = f.w;
    }
    unsigned int w = 0;
    for (int b = 0; b < cB; ++b) {
        const float4* pr = (const float4*)(pl + b * 68);
        float acc = 0.f;
#pragma unroll
        for (int e4 = 0; e4 < cE / 4; ++e4) {
            float4 f = pr[e4];
            acc = fmaf(qv[4*e4+0], f.x, acc);
            acc = fmaf(qv[4*e4+1], f.y, acc);
            acc = fmaf(qv[4*e4+2], f.z, acc);
            acc = fmaf(qv[4*e4+3], f.w, acc);
        }
        acc += pl[b * 68 + 64];
        if (acc > 0.f) w |= (1u << b);
    }
    bits[idx] = w;
}

// ---------------- Kernel 2: one Lloyd iteration (update fused in) --------
// grid = 16 nh x 16 tiles = 256 blocks x 128 thr (1 point/thread).
// scb_it recomputed locally (cents[it-1] + ghist[it-1], integer-exact);
// tile 0 writes cents[it]. Last call (it==cIT) writes cl + pcounts only.
// 4 independent min chains (min assoc/comm on packed keys -> same argmin);
// distinct-cluster ballot loop (1 iter per distinct bc in wave).
__global__ __launch_bounds__(128)
void k_lloyd(const unsigned int* __restrict__ bits, int* __restrict__ ghist,
             unsigned int* __restrict__ cents, int* __restrict__ cl,
             int* __restrict__ pcounts, int it)
{
    __shared__ unsigned int scb[cC] __attribute__((aligned(16)));
    __shared__ int hist[HW];
    int tid = threadIdx.x, lane = tid & 63;
    int tile = blockIdx.x & (NT - 1), nh = blockIdx.x / NT;
    // ---- reconstruct scb_it (identical in every block of this nh) -------
    if (it == 0) {
        if (tid < cC) {
            // linspace(0,L-1,C).astype(int32): floor(c*2047/127), endpoint exact
            int i0 = (int)(((double)tid * 2047.0) / 127.0);
            scb[tid] = bits[(size_t)nh * cL + i0];
        }
    } else {
        const unsigned int* cp = cents + (size_t)(it - 1) * cNH * cC + nh * cC;
        const int* gb = ghist + (size_t)((it - 1) * cNH + nh) * HW;
        if (tid < cC) {
            unsigned int oldc = cp[tid];
            int cnt = gb[4096 + tid];
            if (cnt > 0) {
                unsigned int nw = 0;
#pragma unroll
                for (int b = 0; b < cB; ++b)
                    if (2 * gb[tid * 32 + b] > cnt) nw |= (1u << b);
                oldc = nw;
            }
            scb[tid] = oldc;
        }
    }
    if (it < cIT) {
        for (int i = tid; i < HW; i += 128) hist[i] = 0;
    } else {
        hist[4096 + tid] = 0;                      // counts region only
    }
    int l = tile * 128 + tid;
    unsigned int w = bits[(size_t)nh * cL + l];
    // per-lane bit ballots (lane b&31 keeps bit b); needed only when updating
    unsigned long long mymb = 0ull;
    if (it < cIT) {
#pragma unroll
        for (int b = 0; b < cB; ++b) {
            unsigned long long m = __ballot((w >> b) & 1u);
            if ((lane & 31) == b) mymb = m;
        }
    }
    __syncthreads();
    if (tile == 0 && it < cIT && tid < cC)
        cents[(size_t)it * cNH * cC + nh * cC + tid] = scb[tid];
    // ---- assignment: packed (hamming<<8)|c min; tie -> lowest c ---------
    // 4 independent chains -> 4x ILP; final combine preserves exact argmin
    const uint4* scb4 = (const uint4*)scb;
    int b0 = 0x7fffffff, b1 = 0x7fffffff, b2 = 0x7fffffff, b3 = 0x7fffffff;
    for (int c4 = 0; c4 < cC / 4; ++c4) {
        uint4 cb = scb4[c4];
        int c = c4 * 4;
        b0 = min(b0, (__popc(w ^ cb.x) << 8) | c);
        b1 = min(b1, (__popc(w ^ cb.y) << 8) | (c + 1));
        b2 = min(b2, (__popc(w ^ cb.z) << 8) | (c + 2));
        b3 = min(b3, (__popc(w ^ cb.w) << 8) | (c + 3));
    }
    int best = min(min(b0, b1), min(b2, b3));
    int bc = best & 255;
    if (it == cIT) cl[(size_t)nh * cL + l] = bc;
    // ---- histogram: distinct-cluster ballot loop ------------------------
    if (it < cIT) {
        unsigned long long rem = ~0ull;
        while (rem) {
            int src = __ffsll((long long)rem) - 1;     // lowest unprocessed lane
            int c = __shfl(bc, src);                   // uniform idx -> readlane
            unsigned long long m = __ballot(bc == c);
            if (lane < cB) {
                int contrib = __popcll(m & mymb);
                if (contrib) atomicAdd(&hist[c * 32 + lane], contrib);
            }
            if (lane == 63) atomicAdd(&hist[4096 + c], __popcll(m));
            rem &= ~m;
        }
        __syncthreads();
        // flush nonzero to this iteration's global buffer
        int* gb = ghist + (size_t)(it * cNH + nh) * HW;
        for (int i = tid; i < HW; i += 128) {
            int v = hist[i];
            if (v) atomicAdd(&gb[i], v);
        }
    } else {
        unsigned long long rem = ~0ull;
        while (rem) {
            int src = __ffsll((long long)rem) - 1;
            int c = __shfl(bc, src);
            unsigned long long m = __ballot(bc == c);
            if (lane == 63) atomicAdd(&hist[4096 + c], __popcll(m));
            rem &= ~m;
        }
        __syncthreads();
        pcounts[(nh * NT + tile) * cC + tid] = hist[4096 + tid];
    }
}

// ---------------- Kernel 2c: rank + (tile0) counts/moff/sched ------------
// grid = 16 nh x 16 tiles = 256 blocks x 128 thr (1 point/thread).
// Each block recomputes counts/moff locally from pcounts (integer-exact).
__global__ __launch_bounds__(128)
void k_rank(const int* __restrict__ cl, const int* __restrict__ pcounts,
            int* __restrict__ counts, int* __restrict__ moff,
            int* __restrict__ sched, int* __restrict__ mlist)
{
    __shared__ int pre[cC];       // exclusive prefix of full counts
    __shared__ int scn[cC];       // full counts
    __shared__ int sbefore[cC];   // sum of pcounts for tiles < mine
    __shared__ int wcnt0[cC];
    int tid = threadIdx.x, lane = tid & 63, wid = tid >> 6;
    int tile = blockIdx.x & (NT - 1), nh = blockIdx.x / NT;
    if (tid < cC) {
        int tot = 0, bef = 0;
        for (int t = 0; t < NT; ++t) {
            int v = pcounts[(nh * NT + t) * cC + tid];
            if (t < tile) bef += v;
            tot += v;
        }
        scn[tid] = tot;
        sbefore[tid] = bef;
    }
    __syncthreads();
    if (tid == 0) {
        int run = 0;
        for (int i = 0; i < cC; ++i) { pre[i] = run; run += scn[i]; }
    }
    __syncthreads();
    if (tile == 0) {                              // block-uniform branch
        if (tid < cC) {
            counts[nh * cC + tid] = scn[tid];
            moff[nh * cC + tid] = pre[tid];
        }
        sched[nh * SLOTS + tid] = -1;
        sched[nh * SLOTS + 128 + tid] = -1;
        __syncthreads();
        if (tid == 0) {
            int slot = 0;
            for (int i = 0; i < cC; ++i) {
                int np = (scn[i] + PARTSZ - 1) / PARTSZ;
                for (int p = 0; p < np; ++p)
                    sched[nh * SLOTS + slot++] = i | (p << 8);
            }
        }
    }
    int l = tile * 128 + tid;
    int bc = cl[(size_t)nh * cL + l];
    unsigned long long ltmask = (1ull << lane) - 1ull;
    int myrank = 0;
    for (int c = 0; c < cC; ++c) {
        unsigned long long m = __ballot(bc == c);
        if (wid == 0 && lane == 0) wcnt0[c] = __popcll(m);
        if (bc == c) myrank = __popcll(m & ltmask);
    }
    __syncthreads();
    int off = pre[bc] + sbefore[bc] + myrank + (wid == 1 ? wcnt0[bc] : 0);
    mlist[(size_t)nh * cL + off] = l;
}

// ---------------- Kernel 3: cluster-mean queries Qg ----------------------
// one block (64 lanes = e) per (nh,c); strict ascending-l chain (bit-exact)
__global__ __launch_bounds__(64)
void k_qg(const float* __restrict__ q, const int* __restrict__ mlist,
          const int* __restrict__ moff, const int* __restrict__ counts,
          float* __restrict__ Qg)
{
    int b = blockIdx.x;                 // nh*cC + c
    int nh = b >> 7;
    int h = nh % cH, n = nh / cH;
    int lane = threadIdx.x;
    int off = moff[b];
    int cnt = counts[b];
    const int* ml = mlist + (size_t)nh * cL + off;
    const float* qb = q + ((size_t)n * cL * cH + h) * cE + lane;
    float acc = 0.f;
    int j = 0;
    for (; j + 4 <= cnt; j += 4) {
        int i0 = ml[j], i1 = ml[j + 1], i2 = ml[j + 2], i3 = ml[j + 3];
        float v0 = qb[(size_t)i0 * cH * cE];
        float v1 = qb[(size_t)i1 * cH * cE];
        float v2 = qb[(size_t)i2 * cH * cE];
        float v3 = qb[(size_t)i3 * cH * cE];
        acc += v0; acc += v1; acc += v2; acc += v3;    // in-order chain
    }
    for (; j < cnt; ++j) acc += qb[(size_t)ml[j] * cH * cE];
    float cs = (float)(cnt > 0 ? cnt : 1);
    Qg[(size_t)b * cE + lane] = acc / cs;
}

// ---------------- Kernel 4a: QK = Qg . k^T  (tiled GEMM, exact chains) ---
__global__ __launch_bounds__(256)
void k_qk_gemm(const float* __restrict__ key, const float* __restrict__ Qg,
               float* __restrict__ QK)
{
    __shared__ float qgT[cE][cC + 2];      // [e][c]
    __shared__ float kT[cE][128 + 2];      // [e][s_local]
    int tid = threadIdx.x;
    int bs = blockIdx.x & 15;              // s-tile
    int nh = blockIdx.x >> 4;
    int h = nh % cH, n = nh / cH;
    const float4* qsrc = (const float4*)(Qg + (size_t)nh * cC * cE);
#pragma unroll
    for (int i = 0; i < 8; ++i) {
        int f = tid + 256 * i;
        int c = f >> 4, e4 = (f & 15) << 2;
        float4 v = qsrc[f];
        qgT[e4+0][c] = v.x; qgT[e4+1][c] = v.y; qgT[e4+2][c] = v.z; qgT[e4+3][c] = v.w;
    }
    const float* kb = key + (size_t)n * cS * cH * cE + (size_t)h * cE;
    int s0 = bs * 128;
#pragma unroll
    for (int i = 0; i < 8; ++i) {
        int f = tid + 256 * i;
        int s = f >> 4, e4 = (f & 15) << 2;
        float4 v = *(const float4*)(kb + (size_t)(s0 + s) * (cH * cE) + e4);
        kT[e4+0][s] = v.x; kT[e4+1][s] = v.y; kT[e4+2][s] = v.z; kT[e4+3][s] = v.w;
    }
    __syncthreads();
    int tx = tid & 15, ty = tid >> 4;
    float acc[8][8];
#pragma unroll
    for (int i = 0; i < 8; ++i)
#pragma unroll
        for (int j = 0; j < 8; ++j) acc[i][j] = 0.f;
    for (int e = 0; e < cE; ++e) {
        float qv[8], kv[8];
#pragma unroll
        for (int i = 0; i < 8; ++i) qv[i] = qgT[e][ty + 16 * i];
#pragma unroll
        for (int j = 0; j < 8; ++j) kv[j] = kT[e][tx + 16 * j];
#pragma unroll
        for (int i = 0; i < 8; ++i)
#pragma unroll
            for (int j = 0; j < 8; ++j)
                acc[i][j] = fmaf(qv[i], kv[j], acc[i][j]);   // ascending-e chain
    }
    float* dst = QK + (size_t)nh * cC * cS + s0;
#pragma unroll
    for (int i = 0; i < 8; ++i)
#pragma unroll
        for (int j = 0; j < 8; ++j)
            dst[(size_t)(ty + 16 * i) * cS + tx + 16 * j] = acc[i][j];
}

// ---------------- Kernel 4b: radix-select top-32 + softmax -> P ----------
__global__ __launch_bounds__(256)
void k_sel(float* __restrict__ QK, int* __restrict__ topk,
           float* __restrict__ abk)
{
    __shared__ int sbins[4 * 257];        // 4 wave copies, bank-staggered
    __shared__ int ired[4];
    __shared__ float fred[4];
    __shared__ unsigned skey[cK];
    __shared__ float sval[cK];
    __shared__ int sidx[cK];
    __shared__ int stopk[cK];
    __shared__ int sDig, sRem, scnt;
    __shared__ float sM;
    int tid = threadIdx.x, lane = tid & 63, wid = tid >> 6;
    int b = blockIdx.x;                  // (n*H + h)*C + c
    float* qrow = QK + (size_t)b * cS;
    float v[8]; unsigned key[8];
#pragma unroll
    for (int j = 0; j < 8; ++j) {
        float f = qrow[tid + j * 256];
        v[j] = f;
        unsigned u = __float_as_uint(f);
        key[j] = (u & 0x80000000u) ? ~u : (u | 0x80000000u);   // monotone map
    }
    if (tid == 0) { sRem = cK; scnt = 0; }
    unsigned pfx = 0;
    for (int pass = 0; pass < 4; ++pass) {
        int sh = 24 - 8 * pass;
        for (int i = tid; i < 4 * 257; i += 256) sbins[i] = 0;
        __syncthreads();
        int rem = sRem;
#pragma unroll
        for (int j = 0; j < 8; ++j) {
            bool cand = (pass == 0) || ((key[j] >> (sh + 8)) == pfx);
            if (cand) atomicAdd(&sbins[wid * 257 + ((key[j] >> sh) & 255)], 1);
        }
        __syncthreads();
        if (wid == 0) {
            int d0 = lane * 4;
            int c0 = sbins[d0] + sbins[257 + d0] + sbins[514 + d0] + sbins[771 + d0];
            int c1 = sbins[d0+1] + sbins[257+d0+1] + sbins[514+d0+1] + sbins[771+d0+1];
            int c2 = sbins[d0+2] + sbins[257+d0+2] + sbins[514+d0+2] + sbins[771+d0+2];
            int c3 = sbins[d0+3] + sbins[257+d0+3] + sbins[514+d0+3] + sbins[771+d0+3];
            int tot = c0 + c1 + c2 + c3;
            int incl = tot;                           // backward inclusive scan
#pragma unroll
            for (int off = 1; off < 64; off <<= 1) {
                int o = __shfl_down(incl, off);
                if (lane + off < 64) incl += o;
            }
            int sufHi = incl - tot;
            int G3 = sufHi, G2 = sufHi + c3, G1 = G2 + c2, G0 = G1 + c1;
            int hit = -1, hG = 0;
            if (G0 < rem && rem <= G0 + c0) { hit = d0 + 0; hG = G0; }
            if (G1 < rem && rem <= G1 + c1) { hit = d0 + 1; hG = G1; }
            if (G2 < rem && rem <= G2 + c2) { hit = d0 + 2; hG = G2; }
            if (G3 < rem && rem <= G3 + c3) { hit = d0 + 3; hG = G3; }
            unsigned long long m = __ballot(hit >= 0);
            int src = __ffsll((long long)m) - 1;
            int dsel = __shfl(hit, src);
            int Gsel = __shfl(hG, src);
            if (lane == 0) { sDig = dsel; sRem = rem - Gsel; }
        }
        __syncthreads();
        pfx = (pfx << 8) | (unsigned)sDig;
    }
    unsigned T = pfx;
    int need = sRem;
    int myT = 0;
#pragma unroll
    for (int j = 0; j < 8; ++j) myT += (key[j] == T);
#pragma unroll
    for (int off = 1; off < 64; off <<= 1) myT += __shfl_xor(myT, off);
    if (lane == 0) ired[wid] = myT;
    __syncthreads();
    int tieTot = ((ired[0] + ired[1]) + ired[2]) + ired[3];
    int tieCut = 0x7fffffff;
    if (tieTot != need) {                 // rare: pick need-th smallest tie index
        int last = -1;
        for (int t = 0; t < need; ++t) {
            int mymin = 0x7fffffff;
#pragma unroll
            for (int j = 0; j < 8; ++j) {
                int idx = tid + j * 256;
                if (key[j] == T && idx > last) mymin = min(mymin, idx);
            }
#pragma unroll
            for (int off = 1; off < 64; off <<= 1)
                mymin = min(mymin, __shfl_xor(mymin, off));
            __syncthreads();
            if (lane == 0) ired[wid] = mymin;
            __syncthreads();
            last = min(min(ired[0], ired[1]), min(ired[2], ired[3]));
        }
        tieCut = last;
    }
    __syncthreads();
    int selm = 0;
#pragma unroll
    for (int j = 0; j < 8; ++j) {
        int idx = tid + j * 256;
        bool s_ = (key[j] > T) || (key[j] == T && idx <= tieCut);
        if (s_) {
            int slot = atomicAdd(&scnt, 1);
            skey[slot] = key[j]; sidx[slot] = idx; sval[slot] = v[j];
            selm |= (1 << j);
        }
    }
    __syncthreads();
    if (tid < cK) {
        unsigned kt = skey[tid]; int it = sidx[tid];
        int rank = 0;
#pragma unroll
        for (int j = 0; j < cK; ++j)
            rank += (skey[j] > kt) || (skey[j] == kt && sidx[j] < it);
        stopk[rank] = it;
        if (rank == 0) sM = sval[tid];
    }
    __syncthreads();
    if (tid < cK) topk[(size_t)b * cK + tid] = stopk[tid];
    float M = sM;
    float e8[8]; float ps = 0.f;
#pragma unroll
    for (int j = 0; j < 8; ++j) { e8[j] = expf(0.125f * (v[j] - M)); ps += e8[j]; }
#pragma unroll
    for (int off = 1; off < 64; off <<= 1) ps += __shfl_xor(ps, off);
    if (lane == 0) fred[wid] = ps;
    __syncthreads();
    float den = ((fred[0] + fred[1]) + fred[2]) + fred[3];
    float ab = 0.f;
#pragma unroll
    for (int j = 0; j < 8; ++j) {
        float P = (selm & (1 << j)) ? 0.f : e8[j] / den;
        ab += P;
        qrow[tid + j * 256] = P;
    }
#pragma unroll
    for (int off = 1; off < 64; off <<= 1) ab += __shfl_xor(ab, off);
    __syncthreads();
    if (lane == 0) fred[wid] = ab;
    __syncthreads();
    if (tid == 0) abk[b] = ((fred[0] + fred[1]) + fred[2]) + fred[3];
}

// ---------------- Kernel 4c: Vb_g partials = P . v (split-K GEMM) --------
__global__ __launch_bounds__(256)
void k_pv(const float* __restrict__ P, const float* __restrict__ val,
          float* __restrict__ part)
{
    __shared__ float pT[64][64 + 2];       // [c_local][s_sub]
    __shared__ float vT[64][cD + 4];       // [s_sub][d]
    int tid = threadIdx.x;
    int ch = blockIdx.x & 1;
    int sk = (blockIdx.x >> 1) & 7;
    int nh = blockIdx.x >> 4;
    int h = nh % cH, n = nh / cH;
    int tx = tid & 15, ty = tid >> 4;
    float acc[4][4];
#pragma unroll
    for (int i = 0; i < 4; ++i)
#pragma unroll
        for (int j = 0; j < 4; ++j) acc[i][j] = 0.f;
    const float* pb = P + ((size_t)nh * cC + ch * 64) * cS;
    const float* vb = val + (size_t)n * cS * cH * cD + (size_t)h * cD;
    for (int sub = 0; sub < CHUNK / 64; ++sub) {
        int s0 = sk * CHUNK + sub * 64;
#pragma unroll
        for (int i = 0; i < 4; ++i) {
            int f = tid + 256 * i;
            int c = f >> 4, s4 = (f & 15) << 2;
            float4 v = *(const float4*)(pb + (size_t)c * cS + s0 + s4);
            pT[c][s4+0] = v.x; pT[c][s4+1] = v.y; pT[c][s4+2] = v.z; pT[c][s4+3] = v.w;
        }
#pragma unroll
        for (int i = 0; i < 4; ++i) {
            int f = tid + 256 * i;
            int ss = f >> 4, d4 = (f & 15) << 2;
            float4 v = *(const float4*)(vb + (size_t)(s0 + ss) * (cH * cD) + d4);
            vT[ss][d4+0] = v.x; vT[ss][d4+1] = v.y; vT[ss][d4+2] = v.z; vT[ss][d4+3] = v.w;
        }
        __syncthreads();
        for (int ss = 0; ss < 64; ++ss) {
            float pv[4];
#pragma unroll
            for (int i = 0; i < 4; ++i) pv[i] = pT[ty + 16 * i][ss];
            float4 vv = *(const float4*)&vT[ss][tx * 4];
#pragma unroll
            for (int i = 0; i < 4; ++i) {
                acc[i][0] = fmaf(pv[i], vv.x, acc[i][0]);
                acc[i][1] = fmaf(pv[i], vv.y, acc[i][1]);
                acc[i][2] = fmaf(pv[i], vv.z, acc[i][2]);
                acc[i][3] = fmaf(pv[i], vv.w, acc[i][3]);
            }
        }
        __syncthreads();
    }
    float* dst = part + (((size_t)sk * cNH + nh) * cC + ch * 64) * cD;
#pragma unroll
    for (int i = 0; i < 4; ++i) {
        float4 o; o.x = acc[i][0]; o.y = acc[i][1]; o.z = acc[i][2]; o.w = acc[i][3];
        *(float4*)(dst + (size_t)(ty + 16 * i) * cD + tx * 4) = o;
    }
}

// ---------------- Kernel 5: scheduled per-cluster epilogue ---------------
// grid = 16 nh x 256 slots; block = 256 thr (4 waves). K half-rows in regs,
// V in LDS; per wave <=4 members (PARTSZ=16). vbg summed inline from the 8
// split-K partials (ascending sk, same chain as the old k_red -> bit-exact).
__global__ __launch_bounds__(256)
void k_out(const float* __restrict__ q, const float* __restrict__ key,
           const float* __restrict__ val, const int* __restrict__ mlist,
           const int* __restrict__ moff, const int* __restrict__ counts,
           const float* __restrict__ abk, const float* __restrict__ part,
           const int* __restrict__ topk, const int* __restrict__ sched,
           float* __restrict__ out)
{
    __shared__ float vlds[cK][cD + 1];   // [k][d]: 2-way alias (free)
    __shared__ float aslds[4][cK];
    __shared__ int   st[cK];
    int tid = threadIdx.x, lane = tid & 63, wid = tid >> 6;
    int nh = blockIdx.x >> 8;
    int slot = blockIdx.x & 255;
    int item = sched[nh * SLOTS + slot];
    if (item < 0) return;                // unused slot
    int c = item & 255, part_i = item >> 8;
    int b = nh * cC + c;
    int h = nh % cH, n = nh / cH;
    if (tid < cK) st[tid] = topk[(size_t)b * cK + tid];
    __syncthreads();
    const float* kb = key + ((size_t)n * cS * cH + h) * cE;
    const float* vb = val + ((size_t)n * cS * cH + h) * cD;
    for (int r = wid; r < cK; r += 4)
        vlds[r][lane] = vb[(size_t)st[r] * cH * cD + lane];
    int k = lane >> 1, hh = lane & 1;
    float4 kreg[8];
    {
        const float* kr = kb + (size_t)st[k] * cH * cE + hh * 32;
#pragma unroll
        for (int j = 0; j < 8; ++j) kreg[j] = ((const float4*)kr)[j];
    }
    // vbg = ascending-sk sum of split-K partials (same chain as old k_red)
    float vbgd = 0.f;
    {
        const float* pp = part + (size_t)b * cD + lane;
#pragma unroll
        for (int sk = 0; sk < SK; ++sk)
            vbgd += pp[(size_t)sk * (cNH * cC * cD)];
    }
    __syncthreads();
    int cnt = counts[b];
    int off = moff[b];
    float scale = 1.0f - abk[b];
    float stf = (lane < cK) ? (float)st[lane] : 0.f;
    const int* ml = mlist + (size_t)nh * cL + off;
    const size_t off1 = (size_t)cN * cL * cH * cD;
    const size_t off2 = off1 + (size_t)cN * cH * cL * cK;
    int mstart = part_i * PARTSZ;
    int mend = min(mstart + PARTSZ, cnt);
    for (int m = mstart + wid; m < mend; m += 4) {   // wave-uniform loop
        int l = ml[m];
        const float* qrow = q + (((size_t)n * cL + l) * cH + h) * cE + hh * 32;
        float4 qf[8];
#pragma unroll
        for (int j = 0; j < 8; ++j) qf[j] = ((const float4*)qrow)[j];
        float partial = 0.f;
#pragma unroll
        for (int j = 0; j < 8; ++j) {
            partial = fmaf(qf[j].x, kreg[j].x, partial);
            partial = fmaf(qf[j].y, kreg[j].y, partial);
            partial = fmaf(qf[j].z, kreg[j].z, partial);
            partial = fmaf(qf[j].w, kreg[j].w, partial);
        }
        float qk = partial + __shfl_xor(partial, 1);   // low half + high half
        float M = qk;
#pragma unroll
        for (int o = 2; o < 64; o <<= 1) M = fmaxf(M, __shfl_xor(M, o));
        float ev = expf(0.125f * (qk - M));
        float den = ev;
#pragma unroll
        for (int o = 2; o < 64; o <<= 1) den += __shfl_xor(den, o);
        float as_ = (ev / den) * scale;                // A_s for my k
        if (!hh) aslds[wid][k] = as_;
        float acc = 0.f;
#pragma unroll
        for (int j = 0; j < cK; ++j)
            acc = fmaf(aslds[wid][j], vlds[j][lane], acc);
        acc += vbgd;
        int qidx = nh * cL + l;
        out[(((size_t)n * cL + l) * cH + h) * cD + lane] = acc;   // (N,L,H,D)
        if (lane < cK) {
            out[off1 + (size_t)qidx * cK + lane] = stf;           // sparse_index
            out[off2 + (size_t)qidx * cK + lane] = aslds[wid][lane]; // A_topk
        }
    }
}

// ---------------- launch -------------------------------------------------
extern "C" void kernel_launch(void* const* d_in, const int* in_sizes, int n_in,
                              void* d_out, int out_size, void* d_ws, size_t ws_size,
                              hipStream_t stream)
{
    (void)in_sizes; (void)n_in; (void)out_size; (void)ws_size;
    const float* q      = (const float*)d_in[0];
    const float* key    = (const float*)d_in[1];
    const float* val    = (const float*)d_in[2];
    const float* planes = (const float*)d_in[3];
    char* w = (char*)d_ws;
    unsigned int* bits = (unsigned int*)w;  w += (size_t)cN * cH * cL * 4;
    int*   cl     = (int*)w;                w += (size_t)cN * cH * cL * 4;
    int*   counts = (int*)w;                w += (size_t)cN * cH * cC * 4;
    float* abk    = (float*)w;              w += (size_t)cN * cH * cC * 4;
    float* Qg     = (float*)w;              w += (size_t)cN * cH * cC * cE * 4;
    int*   topkp  = (int*)w;                w += (size_t)cN * cH * cC * cK * 4;
    float* QK     = (float*)w;              w += (size_t)cNH * cC * cS * 4;      // 16 MB
    float* part   = (float*)w;              w += (size_t)SK * cNH * cC * cD * 4; // 4 MB
    int*   ghist  = (int*)w;                w += (size_t)NBUF * cNH * HW * 4;    // 2.97 MB
    unsigned int* cents = (unsigned int*)w; w += (size_t)NBUF * cNH * cC * 4;    // 90 KB
    int*   pcounts= (int*)w;                w += (size_t)cNH * NT * cC * 4;      // 128 KB
    int*   mlist  = (int*)w;                w += (size_t)cNH * cL * 4;           // 128 KB
    int*   moff   = (int*)w;                w += (size_t)cNH * cC * 4;           // 8 KB
    int*   sched  = (int*)w;                w += (size_t)cNH * SLOTS * 4;        // 16 KB
    float* out = (float*)d_out;

    k_bits <<<(cN * cH * cL) / 256, 256, 0, stream>>>(q, planes, bits, ghist);
    for (int it = 0; it <= cIT; ++it)
        k_lloyd <<<cNH * NT, 128, 0, stream>>>(bits, ghist, cents, cl, pcounts, it);
    k_rank <<<cNH * NT, 128, 0, stream>>>(cl, pcounts, counts, moff, sched, mlist);
    k_qg     <<<cNH * cC, 64, 0, stream>>>(q, mlist, moff, counts, Qg);
    k_qk_gemm<<<cNH * 16, 256, 0, stream>>>(key, Qg, QK);
    k_sel    <<<cNH * cC, 256, 0, stream>>>(QK, topkp, abk);
    k_pv     <<<cNH * SK * 2, 256, 0, stream>>>(QK, val, part);
    k_out    <<<cNH * SLOTS, 256, 0, stream>>>(q, key, val, mlist, moff, counts,
                                               abk, part, topkp, sched, out);
}

// Round 19
// 274.443 us; speedup vs baseline: 1.3036x; 1.1284x over previous
//
#include <hip/hip_runtime.h>
#include <math.h>

constexpr int cN = 2, cH = 8, cL = 2048, cS = 2048, cE = 64, cD = 64;
constexpr int cC = 128, cK = 32, cB = 32, cIT = 10;
constexpr int cNH = cN * cH;          // 16
constexpr int SK = 8;                 // split-K factor for PV
constexpr int CHUNK = cS / SK;        // 256 s per split
constexpr int NT = 8;                 // point tiles per nh (256 points each)
constexpr int HW = cC * 33;           // hist words: sbs[128][32] + scnt[128] = 4224
constexpr int NBUF = cIT + 1;         // 11 ghist buffers (one per iteration)
// TEMP = 1/sqrt(64) = 0.125 exactly

// ---------------- Kernel 1: LSH bits + zero ghist ------------------------
__global__ __launch_bounds__(256)
void k_bits(const float* __restrict__ q, const float* __restrict__ planes,
            unsigned int* __restrict__ bits, int* __restrict__ ghist)
{
    __shared__ float pl[cB * 68];               // padded rows, 16B-aligned
    int tid = threadIdx.x;
    for (int i = tid; i < cB * (cE + 1); i += 256) {
        int b = i / 65, e = i % 65;
        pl[b * 68 + e] = planes[i];
    }
    {   // zero my slice of the 11 global hist buffers
        const int ZS = NBUF * cNH * HW / 128;   // 5808 (grid = 128 blocks)
        for (int i = tid; i < ZS; i += 256) ghist[(size_t)blockIdx.x * ZS + i] = 0;
    }
    __syncthreads();
    int idx = blockIdx.x * 256 + tid;           // (n*H + h)*L + l
    int l = idx % cL, h = (idx / cL) % cH, n = idx / (cL * cH);
    const float* qr = q + (((size_t)n * cL + l) * cH + h) * cE;
    float qv[cE];
#pragma unroll
    for (int e4 = 0; e4 < cE / 4; ++e4) {
        float4 f = ((const float4*)qr)[e4];
        qv[4*e4+0] = f.x; qv[4*e4+1] = f.y; qv[4*e4+2] = f.z; qv[4*e4+3] = f.w;
    }
    unsigned int w = 0;
    for (int b = 0; b < cB; ++b) {
        const float4* pr = (const float4*)(pl + b * 68);
        float acc = 0.f;
#pragma unroll
        for (int e4 = 0; e4 < cE / 4; ++e4) {
            float4 f = pr[e4];
            acc = fmaf(qv[4*e4+0], f.x, acc);
            acc = fmaf(qv[4*e4+1], f.y, acc);
            acc = fmaf(qv[4*e4+2], f.z, acc);
            acc = fmaf(qv[4*e4+3], f.w, acc);
        }
        acc += pl[b * 68 + 64];
        if (acc > 0.f) w |= (1u << b);
    }
    bits[idx] = w;
}

// ---------------- Kernel 2: one Lloyd iteration (update fused in) --------
// grid = 16 nh x 8 tiles = 128 blocks x 256 thr (1 point/thread).
// scb_it recomputed locally (cents[it-1] + ghist[it-1], integer-exact);
// tile 0 writes cents[it]. Last call (it==cIT) writes cl + pcounts only.
__global__ __launch_bounds__(256)
void k_lloyd(const unsigned int* __restrict__ bits, int* __restrict__ ghist,
             unsigned int* __restrict__ cents, int* __restrict__ cl,
             int* __restrict__ pcounts, int it)
{
    __shared__ unsigned int scb[cC] __attribute__((aligned(16)));
    __shared__ int hist[HW];
    int tid = threadIdx.x, lane = tid & 63;
    int tile = blockIdx.x & (NT - 1), nh = blockIdx.x / NT;
    // ---- reconstruct scb_it (identical in every block of this nh) -------
    if (it == 0) {
        if (tid < cC) {
            // linspace(0,L-1,C).astype(int32): floor(c*2047/127), endpoint exact
            int i0 = (int)(((double)tid * 2047.0) / 127.0);
            scb[tid] = bits[(size_t)nh * cL + i0];
        }
    } else {
        const unsigned int* cp = cents + (size_t)(it - 1) * cNH * cC + nh * cC;
        const int* gb = ghist + (size_t)((it - 1) * cNH + nh) * HW;
        if (tid < cC) {
            unsigned int oldc = cp[tid];
            int cnt = gb[4096 + tid];
            if (cnt > 0) {
                unsigned int nw = 0;
#pragma unroll
                for (int b = 0; b < cB; ++b)
                    if (2 * gb[tid * 32 + b] > cnt) nw |= (1u << b);
                oldc = nw;
            }
            scb[tid] = oldc;
        }
    }
    if (it < cIT) {
        for (int i = tid; i < HW; i += 256) hist[i] = 0;
    } else {
        if (tid < cC) hist[4096 + tid] = 0;        // counts region only
    }
    int l = tile * 256 + tid;
    unsigned int w = bits[(size_t)nh * cL + l];
    // per-lane bit ballots (lane b&31 keeps bit b); needed only when updating
    unsigned long long mymb = 0ull;
    if (it < cIT) {
#pragma unroll
        for (int b = 0; b < cB; ++b) {
            unsigned long long m = __ballot((w >> b) & 1u);
            if ((lane & 31) == b) mymb = m;
        }
    }
    __syncthreads();
    if (tile == 0 && it < cIT && tid < cC)
        cents[(size_t)it * cNH * cC + nh * cC + tid] = scb[tid];
    // ---- assignment: packed (hamming<<8)|c min; tie -> lowest c ---------
    // 4 independent chains -> 4x ILP; final combine preserves exact argmin
    const uint4* scb4 = (const uint4*)scb;
    int b0 = 0x7fffffff, b1 = 0x7fffffff, b2 = 0x7fffffff, b3 = 0x7fffffff;
    for (int c4 = 0; c4 < cC / 4; ++c4) {
        uint4 cb = scb4[c4];
        int c = c4 * 4;
        b0 = min(b0, (__popc(w ^ cb.x) << 8) | c);
        b1 = min(b1, (__popc(w ^ cb.y) << 8) | (c + 1));
        b2 = min(b2, (__popc(w ^ cb.z) << 8) | (c + 2));
        b3 = min(b3, (__popc(w ^ cb.w) << 8) | (c + 3));
    }
    int best = min(min(b0, b1), min(b2, b3));
    int bc = best & 255;
    if (it == cIT) cl[(size_t)nh * cL + l] = bc;
    // ---- histogram: distinct-cluster ballot loop ------------------------
    if (it < cIT) {
        unsigned long long rem = ~0ull;
        while (rem) {
            int src = __ffsll((long long)rem) - 1;     // lowest unprocessed lane
            int c = __shfl(bc, src);                   // uniform idx -> readlane
            unsigned long long m = __ballot(bc == c);
            if (lane < cB) {
                int contrib = __popcll(m & mymb);
                if (contrib) atomicAdd(&hist[c * 32 + lane], contrib);
            }
            if (lane == 63) atomicAdd(&hist[4096 + c], __popcll(m));
            rem &= ~m;
        }
        __syncthreads();
        // flush nonzero to this iteration's global buffer
        int* gb = ghist + (size_t)(it * cNH + nh) * HW;
        for (int i = tid; i < HW; i += 256) {
            int v = hist[i];
            if (v) atomicAdd(&gb[i], v);
        }
    } else {
        unsigned long long rem = ~0ull;
        while (rem) {
            int src = __ffsll((long long)rem) - 1;
            int c = __shfl(bc, src);
            unsigned long long m = __ballot(bc == c);
            if (lane == 63) atomicAdd(&hist[4096 + c], __popcll(m));
            rem &= ~m;
        }
        __syncthreads();
        if (tid < cC) pcounts[(nh * NT + tile) * cC + tid] = hist[4096 + tid];
    }
}

// ---------------- Kernel 2c: rank + (tile0) counts/moff ------------------
// grid = 16 nh x 8 tiles = 128 blocks x 256 thr (1 point/thread).
// Each block recomputes counts/moff locally from pcounts (integer-exact).
__global__ __launch_bounds__(256)
void k_rank(const int* __restrict__ cl, const int* __restrict__ pcounts,
            int* __restrict__ counts, int* __restrict__ moff,
            int* __restrict__ mlist)
{
    __shared__ int pre[cC];       // exclusive prefix of full counts
    __shared__ int scn[cC];       // full counts
    __shared__ int sbefore[cC];   // sum of pcounts for tiles < mine
    __shared__ int wcnt[4][cC];   // per-wave member counts
    int tid = threadIdx.x, lane = tid & 63, wid = tid >> 6;
    int tile = blockIdx.x & (NT - 1), nh = blockIdx.x / NT;
    if (tid < cC) {
        int tot = 0, bef = 0;
        for (int t = 0; t < NT; ++t) {
            int v = pcounts[(nh * NT + t) * cC + tid];
            if (t < tile) bef += v;
            tot += v;
        }
        scn[tid] = tot;
        sbefore[tid] = bef;
    }
    {   // zero wcnt
        int* wf = &wcnt[0][0];
        for (int i = tid; i < 4 * cC; i += 256) wf[i] = 0;
    }
    __syncthreads();
    if (tid == 0) {
        int run = 0;
        for (int i = 0; i < cC; ++i) { pre[i] = run; run += scn[i]; }
    }
    __syncthreads();
    if (tile == 0) {                              // block-uniform branch
        if (tid < cC) {
            counts[nh * cC + tid] = scn[tid];
            moff[nh * cC + tid] = pre[tid];
        }
    }
    int l = tile * 256 + tid;
    int bc = cl[(size_t)nh * cL + l];
    unsigned long long ltmask = (1ull << lane) - 1ull;
    int myrank = 0;
    {   // distinct-cluster loop fills wcnt[wid][*] and myrank
        unsigned long long rem = ~0ull;
        while (rem) {
            int src = __ffsll((long long)rem) - 1;
            int c = __shfl(bc, src);
            unsigned long long m = __ballot(bc == c);
            if (lane == 0) wcnt[wid][c] = __popcll(m);
            if (bc == c) myrank = __popcll(m & ltmask);
            rem &= ~m;
        }
    }
    __syncthreads();
    int off = pre[bc] + sbefore[bc] + myrank;
    for (int w2 = 0; w2 < 4; ++w2)
        if (w2 < wid) off += wcnt[w2][bc];
    mlist[(size_t)nh * cL + off] = l;
}

// ---------------- Kernel 3: cluster-mean queries Qg ----------------------
// one block (64 lanes = e) per (nh,c); strict ascending-l chain (bit-exact)
__global__ __launch_bounds__(64)
void k_qg(const float* __restrict__ q, const int* __restrict__ mlist,
          const int* __restrict__ moff, const int* __restrict__ counts,
          float* __restrict__ Qg)
{
    int b = blockIdx.x;                 // nh*cC + c
    int nh = b >> 7;
    int h = nh % cH, n = nh / cH;
    int lane = threadIdx.x;
    int off = moff[b];
    int cnt = counts[b];
    const int* ml = mlist + (size_t)nh * cL + off;
    const float* qb = q + ((size_t)n * cL * cH + h) * cE + lane;
    float acc = 0.f;
    int j = 0;
    for (; j + 4 <= cnt; j += 4) {
        int i0 = ml[j], i1 = ml[j + 1], i2 = ml[j + 2], i3 = ml[j + 3];
        float v0 = qb[(size_t)i0 * cH * cE];
        float v1 = qb[(size_t)i1 * cH * cE];
        float v2 = qb[(size_t)i2 * cH * cE];
        float v3 = qb[(size_t)i3 * cH * cE];
        acc += v0; acc += v1; acc += v2; acc += v3;    // in-order chain
    }
    for (; j < cnt; ++j) acc += qb[(size_t)ml[j] * cH * cE];
    float cs = (float)(cnt > 0 ? cnt : 1);
    Qg[(size_t)b * cE + lane] = acc / cs;
}

// ---------------- Kernel 4a: QK = Qg . k^T  (tiled GEMM, exact chains) ---
__global__ __launch_bounds__(256)
void k_qk_gemm(const float* __restrict__ key, const float* __restrict__ Qg,
               float* __restrict__ QK)
{
    __shared__ float qgT[cE][cC + 2];      // [e][c]
    __shared__ float kT[cE][128 + 2];      // [e][s_local]
    int tid = threadIdx.x;
    int bs = blockIdx.x & 15;              // s-tile
    int nh = blockIdx.x >> 4;
    int h = nh % cH, n = nh / cH;
    const float4* qsrc = (const float4*)(Qg + (size_t)nh * cC * cE);
#pragma unroll
    for (int i = 0; i < 8; ++i) {
        int f = tid + 256 * i;
        int c = f >> 4, e4 = (f & 15) << 2;
        float4 v = qsrc[f];
        qgT[e4+0][c] = v.x; qgT[e4+1][c] = v.y; qgT[e4+2][c] = v.z; qgT[e4+3][c] = v.w;
    }
    const float* kb = key + (size_t)n * cS * cH * cE + (size_t)h * cE;
    int s0 = bs * 128;
#pragma unroll
    for (int i = 0; i < 8; ++i) {
        int f = tid + 256 * i;
        int s = f >> 4, e4 = (f & 15) << 2;
        float4 v = *(const float4*)(kb + (size_t)(s0 + s) * (cH * cE) + e4);
        kT[e4+0][s] = v.x; kT[e4+1][s] = v.y; kT[e4+2][s] = v.z; kT[e4+3][s] = v.w;
    }
    __syncthreads();
    int tx = tid & 15, ty = tid >> 4;
    float acc[8][8];
#pragma unroll
    for (int i = 0; i < 8; ++i)
#pragma unroll
        for (int j = 0; j < 8; ++j) acc[i][j] = 0.f;
    for (int e = 0; e < cE; ++e) {
        float qv[8], kv[8];
#pragma unroll
        for (int i = 0; i < 8; ++i) qv[i] = qgT[e][ty + 16 * i];
#pragma unroll
        for (int j = 0; j < 8; ++j) kv[j] = kT[e][tx + 16 * j];
#pragma unroll
        for (int i = 0; i < 8; ++i)
#pragma unroll
            for (int j = 0; j < 8; ++j)
                acc[i][j] = fmaf(qv[i], kv[j], acc[i][j]);   // ascending-e chain
    }
    float* dst = QK + (size_t)nh * cC * cS + s0;
#pragma unroll
    for (int i = 0; i < 8; ++i)
#pragma unroll
        for (int j = 0; j < 8; ++j)
            dst[(size_t)(ty + 16 * i) * cS + tx + 16 * j] = acc[i][j];
}

// ---------------- Kernel 4b: radix-select top-32 + softmax -> P ----------
__global__ __launch_bounds__(256)
void k_sel(float* __restrict__ QK, int* __restrict__ topk,
           float* __restrict__ abk)
{
    __shared__ int sbins[4 * 257];        // 4 wave copies, bank-staggered
    __shared__ int ired[4];
    __shared__ float fred[4];
    __shared__ unsigned skey[cK];
    __shared__ float sval[cK];
    __shared__ int sidx[cK];
    __shared__ int stopk[cK];
    __shared__ int sDig, sRem, scnt;
    __shared__ float sM;
    int tid = threadIdx.x, lane = tid & 63, wid = tid >> 6;
    int b = blockIdx.x;                  // (n*H + h)*C + c
    float* qrow = QK + (size_t)b * cS;
    float v[8]; unsigned key[8];
#pragma unroll
    for (int j = 0; j < 8; ++j) {
        float f = qrow[tid + j * 256];
        v[j] = f;
        unsigned u = __float_as_uint(f);
        key[j] = (u & 0x80000000u) ? ~u : (u | 0x80000000u);   // monotone map
    }
    if (tid == 0) { sRem = cK; scnt = 0; }
    unsigned pfx = 0;
    for (int pass = 0; pass < 4; ++pass) {
        int sh = 24 - 8 * pass;
        for (int i = tid; i < 4 * 257; i += 256) sbins[i] = 0;
        __syncthreads();
        int rem = sRem;
#pragma unroll
        for (int j = 0; j < 8; ++j) {
            bool cand = (pass == 0) || ((key[j] >> (sh + 8)) == pfx);
            if (cand) atomicAdd(&sbins[wid * 257 + ((key[j] >> sh) & 255)], 1);
        }
        __syncthreads();
        if (wid == 0) {
            int d0 = lane * 4;
            int c0 = sbins[d0] + sbins[257 + d0] + sbins[514 + d0] + sbins[771 + d0];
            int c1 = sbins[d0+1] + sbins[257+d0+1] + sbins[514+d0+1] + sbins[771+d0+1];
            int c2 = sbins[d0+2] + sbins[257+d0+2] + sbins[514+d0+2] + sbins[771+d0+2];
            int c3 = sbins[d0+3] + sbins[257+d0+3] + sbins[514+d0+3] + sbins[771+d0+3];
            int tot = c0 + c1 + c2 + c3;
            int incl = tot;                           // backward inclusive scan
#pragma unroll
            for (int off = 1; off < 64; off <<= 1) {
                int o = __shfl_down(incl, off);
                if (lane + off < 64) incl += o;
            }
            int sufHi = incl - tot;
            int G3 = sufHi, G2 = sufHi + c3, G1 = G2 + c2, G0 = G1 + c1;
            int hit = -1, hG = 0;
            if (G0 < rem && rem <= G0 + c0) { hit = d0 + 0; hG = G0; }
            if (G1 < rem && rem <= G1 + c1) { hit = d0 + 1; hG = G1; }
            if (G2 < rem && rem <= G2 + c2) { hit = d0 + 2; hG = G2; }
            if (G3 < rem && rem <= G3 + c3) { hit = d0 + 3; hG = G3; }
            unsigned long long m = __ballot(hit >= 0);
            int src = __ffsll((long long)m) - 1;
            int dsel = __shfl(hit, src);
            int Gsel = __shfl(hG, src);
            if (lane == 0) { sDig = dsel; sRem = rem - Gsel; }
        }
        __syncthreads();
        pfx = (pfx << 8) | (unsigned)sDig;
    }
    unsigned T = pfx;
    int need = sRem;
    int myT = 0;
#pragma unroll
    for (int j = 0; j < 8; ++j) myT += (key[j] == T);
#pragma unroll
    for (int off = 1; off < 64; off <<= 1) myT += __shfl_xor(myT, off);
    if (lane == 0) ired[wid] = myT;
    __syncthreads();
    int tieTot = ((ired[0] + ired[1]) + ired[2]) + ired[3];
    int tieCut = 0x7fffffff;
    if (tieTot != need) {                 // rare: pick need-th smallest tie index
        int last = -1;
        for (int t = 0; t < need; ++t) {
            int mymin = 0x7fffffff;
#pragma unroll
            for (int j = 0; j < 8; ++j) {
                int idx = tid + j * 256;
                if (key[j] == T && idx > last) mymin = min(mymin, idx);
            }
#pragma unroll
            for (int off = 1; off < 64; off <<= 1)
                mymin = min(mymin, __shfl_xor(mymin, off));
            __syncthreads();
            if (lane == 0) ired[wid] = mymin;
            __syncthreads();
            last = min(min(ired[0], ired[1]), min(ired[2], ired[3]));
        }
        tieCut = last;
    }
    __syncthreads();
    int selm = 0;
#pragma unroll
    for (int j = 0; j < 8; ++j) {
        int idx = tid + j * 256;
        bool s_ = (key[j] > T) || (key[j] == T && idx <= tieCut);
        if (s_) {
            int slot = atomicAdd(&scnt, 1);
            skey[slot] = key[j]; sidx[slot] = idx; sval[slot] = v[j];
            selm |= (1 << j);
        }
    }
    __syncthreads();
    if (tid < cK) {
        unsigned kt = skey[tid]; int it = sidx[tid];
        int rank = 0;
#pragma unroll
        for (int j = 0; j < cK; ++j)
            rank += (skey[j] > kt) || (skey[j] == kt && sidx[j] < it);
        stopk[rank] = it;
        if (rank == 0) sM = sval[tid];
    }
    __syncthreads();
    if (tid < cK) topk[(size_t)b * cK + tid] = stopk[tid];
    float M = sM;
    float e8[8]; float ps = 0.f;
#pragma unroll
    for (int j = 0; j < 8; ++j) { e8[j] = expf(0.125f * (v[j] - M)); ps += e8[j]; }
#pragma unroll
    for (int off = 1; off < 64; off <<= 1) ps += __shfl_xor(ps, off);
    if (lane == 0) fred[wid] = ps;
    __syncthreads();
    float den = ((fred[0] + fred[1]) + fred[2]) + fred[3];
    float ab = 0.f;
#pragma unroll
    for (int j = 0; j < 8; ++j) {
        float P = (selm & (1 << j)) ? 0.f : e8[j] / den;
        ab += P;
        qrow[tid + j * 256] = P;
    }
#pragma unroll
    for (int off = 1; off < 64; off <<= 1) ab += __shfl_xor(ab, off);
    __syncthreads();
    if (lane == 0) fred[wid] = ab;
    __syncthreads();
    if (tid == 0) abk[b] = ((fred[0] + fred[1]) + fred[2]) + fred[3];
}

// ---------------- Kernel 4c: Vb_g partials = P . v (split-K GEMM) --------
__global__ __launch_bounds__(256)
void k_pv(const float* __restrict__ P, const float* __restrict__ val,
          float* __restrict__ part)
{
    __shared__ float pT[64][64 + 2];       // [c_local][s_sub]
    __shared__ float vT[64][cD + 4];       // [s_sub][d]
    int tid = threadIdx.x;
    int ch = blockIdx.x & 1;
    int sk = (blockIdx.x >> 1) & 7;
    int nh = blockIdx.x >> 4;
    int h = nh % cH, n = nh / cH;
    int tx = tid & 15, ty = tid >> 4;
    float acc[4][4];
#pragma unroll
    for (int i = 0; i < 4; ++i)
#pragma unroll
        for (int j = 0; j < 4; ++j) acc[i][j] = 0.f;
    const float* pb = P + ((size_t)nh * cC + ch * 64) * cS;
    const float* vb = val + (size_t)n * cS * cH * cD + (size_t)h * cD;
    for (int sub = 0; sub < CHUNK / 64; ++sub) {
        int s0 = sk * CHUNK + sub * 64;
#pragma unroll
        for (int i = 0; i < 4; ++i) {
            int f = tid + 256 * i;
            int c = f >> 4, s4 = (f & 15) << 2;
            float4 v = *(const float4*)(pb + (size_t)c * cS + s0 + s4);
            pT[c][s4+0] = v.x; pT[c][s4+1] = v.y; pT[c][s4+2] = v.z; pT[c][s4+3] = v.w;
        }
#pragma unroll
        for (int i = 0; i < 4; ++i) {
            int f = tid + 256 * i;
            int ss = f >> 4, d4 = (f & 15) << 2;
            float4 v = *(const float4*)(vb + (size_t)(s0 + ss) * (cH * cD) + d4);
            vT[ss][d4+0] = v.x; vT[ss][d4+1] = v.y; vT[ss][d4+2] = v.z; vT[ss][d4+3] = v.w;
        }
        __syncthreads();
        for (int ss = 0; ss < 64; ++ss) {
            float pv[4];
#pragma unroll
            for (int i = 0; i < 4; ++i) pv[i] = pT[ty + 16 * i][ss];
            float4 vv = *(const float4*)&vT[ss][tx * 4];
#pragma unroll
            for (int i = 0; i < 4; ++i) {
                acc[i][0] = fmaf(pv[i], vv.x, acc[i][0]);
                acc[i][1] = fmaf(pv[i], vv.y, acc[i][1]);
                acc[i][2] = fmaf(pv[i], vv.z, acc[i][2]);
                acc[i][3] = fmaf(pv[i], vv.w, acc[i][3]);
            }
        }
        __syncthreads();
    }
    float* dst = part + (((size_t)sk * cNH + nh) * cC + ch * 64) * cD;
#pragma unroll
    for (int i = 0; i < 4; ++i) {
        float4 o; o.x = acc[i][0]; o.y = acc[i][1]; o.z = acc[i][2]; o.w = acc[i][3];
        *(float4*)(dst + (size_t)(ty + 16 * i) * cD + tx * 4) = o;
    }
}

// ---------------- Kernel 5: per-cluster epilogue (K regs, R11 form) ------
// one block per (nh,c); V in LDS, K half-rows in registers; 4 waves stride
// the member list. vbg summed inline from the 8 split-K partials
// (ascending sk, same chain as old k_red). FP chains operand-identical
// to the validated kernel -> bit-identical outputs.
__global__ __launch_bounds__(256)
void k_out(const float* __restrict__ q, const float* __restrict__ key,
           const float* __restrict__ val, const int* __restrict__ mlist,
           const int* __restrict__ moff, const int* __restrict__ counts,
           const float* __restrict__ abk, const float* __restrict__ part,
           const int* __restrict__ topk, float* __restrict__ out)
{
    __shared__ float vlds[cK][cD + 1];   // [k][d]: 2-way alias (free)
    __shared__ float aslds[4][cK];
    __shared__ int   st[cK];
    int tid = threadIdx.x, lane = tid & 63, wid = tid >> 6;
    int b = blockIdx.x;                 // nh*cC + c
    int nh = b >> 7;
    int h = nh % cH, n = nh / cH;
    if (tid < cK) st[tid] = topk[(size_t)b * cK + tid];
    __syncthreads();
    const float* kb = key + ((size_t)n * cS * cH + h) * cE;
    const float* vb = val + ((size_t)n * cS * cH + h) * cD;
    for (int r = wid; r < cK; r += 4)
        vlds[r][lane] = vb[(size_t)st[r] * cH * cD + lane];
    int k = lane >> 1, hh = lane & 1;
    float4 kreg[8];
    {
        const float* kr = kb + (size_t)st[k] * cH * cE + hh * 32;
#pragma unroll
        for (int j = 0; j < 8; ++j) kreg[j] = ((const float4*)kr)[j];
    }
    // vbg = ascending-sk sum of split-K partials (same chain as old k_red)
    float vbgd = 0.f;
    {
        const float* pp = part + (size_t)b * cD + lane;
#pragma unroll
        for (int sk = 0; sk < SK; ++sk)
            vbgd += pp[(size_t)sk * (cNH * cC * cD)];
    }
    __syncthreads();
    int cnt = counts[b];
    int off = moff[b];
    float scale = 1.0f - abk[b];
    float stf = (lane < cK) ? (float)st[lane] : 0.f;
    const int* ml = mlist + (size_t)nh * cL + off;
    const size_t off1 = (size_t)cN * cL * cH * cD;
    const size_t off2 = off1 + (size_t)cN * cH * cL * cK;
    for (int m = wid; m < cnt; m += 4) {             // wave-uniform loop
        int l = ml[m];
        const float* qrow = q + (((size_t)n * cL + l) * cH + h) * cE + hh * 32;
        float4 qf[8];
#pragma unroll
        for (int j = 0; j < 8; ++j) qf[j] = ((const float4*)qrow)[j];
        float partial = 0.f;
#pragma unroll
        for (int j = 0; j < 8; ++j) {
            partial = fmaf(qf[j].x, kreg[j].x, partial);
            partial = fmaf(qf[j].y, kreg[j].y, partial);
            partial = fmaf(qf[j].z, kreg[j].z, partial);
            partial = fmaf(qf[j].w, kreg[j].w, partial);
        }
        float qk = partial + __shfl_xor(partial, 1);   // low half + high half
        float M = qk;
#pragma unroll
        for (int o = 2; o < 64; o <<= 1) M = fmaxf(M, __shfl_xor(M, o));
        float ev = expf(0.125f * (qk - M));
        float den = ev;
#pragma unroll
        for (int o = 2; o < 64; o <<= 1) den += __shfl_xor(den, o);
        float as_ = (ev / den) * scale;                // A_s for my k
        if (!hh) aslds[wid][k] = as_;
        float acc = 0.f;
#pragma unroll
        for (int j = 0; j < cK; ++j)
            acc = fmaf(aslds[wid][j], vlds[j][lane], acc);
        acc += vbgd;
        int qidx = nh * cL + l;
        out[(((size_t)n * cL + l) * cH + h) * cD + lane] = acc;   // (N,L,H,D)
        if (lane < cK) {
            out[off1 + (size_t)qidx * cK + lane] = stf;           // sparse_index
            out[off2 + (size_t)qidx * cK + lane] = aslds[wid][lane]; // A_topk
        }
    }
}

// ---------------- launch -------------------------------------------------
extern "C" void kernel_launch(void* const* d_in, const int* in_sizes, int n_in,
                              void* d_out, int out_size, void* d_ws, size_t ws_size,
                              hipStream_t stream)
{
    (void)in_sizes; (void)n_in; (void)out_size; (void)ws_size;
    const float* q      = (const float*)d_in[0];
    const float* key    = (const float*)d_in[1];
    const float* val    = (const float*)d_in[2];
    const float* planes = (const float*)d_in[3];
    char* w = (char*)d_ws;
    unsigned int* bits = (unsigned int*)w;  w += (size_t)cN * cH * cL * 4;
    int*   cl     = (int*)w;                w += (size_t)cN * cH * cL * 4;
    int*   counts = (int*)w;                w += (size_t)cN * cH * cC * 4;
    float* abk    = (float*)w;              w += (size_t)cN * cH * cC * 4;
    float* Qg     = (float*)w;              w += (size_t)cN * cH * cC * cE * 4;
    int*   topkp  = (int*)w;                w += (size_t)cN * cH * cC * cK * 4;
    float* QK     = (float*)w;              w += (size_t)cNH * cC * cS * 4;      // 16 MB
    float* part   = (float*)w;              w += (size_t)SK * cNH * cC * cD * 4; // 4 MB
    int*   ghist  = (int*)w;                w += (size_t)NBUF * cNH * HW * 4;    // 2.97 MB
    unsigned int* cents = (unsigned int*)w; w += (size_t)NBUF * cNH * cC * 4;    // 90 KB
    int*   pcounts= (int*)w;                w += (size_t)cNH * NT * cC * 4;      // 64 KB
    int*   mlist  = (int*)w;                w += (size_t)cNH * cL * 4;           // 128 KB
    int*   moff   = (int*)w;                w += (size_t)cNH * cC * 4;           // 8 KB
    float* out = (float*)d_out;

    k_bits <<<(cN * cH * cL) / 256, 256, 0, stream>>>(q, planes, bits, ghist);
    for (int it = 0; it <= cIT; ++it)
        k_lloyd <<<cNH * NT, 256, 0, stream>>>(bits, ghist, cents, cl, pcounts, it);
    k_rank <<<cNH * NT, 256, 0, stream>>>(cl, pcounts, counts, moff, mlist);
    k_qg     <<<cNH * cC, 64, 0, stream>>>(q, mlist, moff, counts, Qg);
    k_qk_gemm<<<cNH * 16, 256, 0, stream>>>(key, Qg, QK);
    k_sel    <<<cNH * cC, 256, 0, stream>>>(QK, topkp, abk);
    k_pv     <<<cNH * SK * 2, 256, 0, stream>>>(QK, val, part);
    k_out    <<<cNH * cC, 256, 0, stream>>>(q, key, val, mlist, moff, counts,
                                            abk, part, topkp, out);
}